// Round 1
// 1050.604 us; speedup vs baseline: 1.2064x; 1.2064x over previous
//
#include <hip/hip_runtime.h>
#include <math.h>

#define BB 2
#define LL 768
#define CC 256
#define CZ 64
#define NH 8
#define NBLK 4
#define HD 32
#define BL (BB*LL)   // 1536

typedef unsigned short ushort_t;
typedef float f32x4 __attribute__((ext_vector_type(4)));
typedef __bf16 bf16x8 __attribute__((ext_vector_type(8)));

__device__ __forceinline__ float gelu_exact(float x) {
    return 0.5f * x * (1.0f + erff(x * 0.70710678118654752f));
}

__device__ __forceinline__ ushort_t f2bf(float f) {
    union { float f; unsigned u; } x; x.f = f;
    unsigned r = x.u + 0x7fffu + ((x.u >> 16) & 1u);
    return (ushort_t)(r >> 16);
}

__device__ __forceinline__ float bf2f(ushort_t u) {
    union { unsigned u; float f; } x; x.u = ((unsigned)u) << 16;
    return x.f;
}

// ---------------- time embedding + MLP -> time_cond (B,256) ----------------
__global__ __launch_bounds__(256) void k_time(
        const float* __restrict__ t,
        const float* __restrict__ tw1, const float* __restrict__ tb1,
        const float* __restrict__ tw2, const float* __restrict__ tb2,
        float* __restrict__ time_cond) {
    __shared__ float temb[256];
    __shared__ float mid[1024];
    int b = blockIdx.x;
    int tid = threadIdx.x;
    if (tid < 128) {
        float f = expf(-logf(10000.0f) * (float)tid / 128.0f);
        float a = t[b] * f;
        temb[tid]       = cosf(a);
        temb[128 + tid] = sinf(a);
    }
    __syncthreads();
    #pragma unroll
    for (int m = 0; m < 4; ++m) {
        int col = tid + 256 * m;
        float acc = tb1[col];
        #pragma unroll 8
        for (int k = 0; k < 256; ++k) acc += temb[k] * tw1[(size_t)k * 1024 + col];
        mid[col] = gelu_exact(acc);
    }
    __syncthreads();
    float acc = tb2[tid];
    #pragma unroll 8
    for (int k = 0; k < 1024; ++k) acc += mid[k] * tw2[(size_t)k * 256 + tid];
    time_cond[b * 256 + tid] = acc;
}

// ---------------- adaln scale/shift tables ---------------------------------
__global__ __launch_bounds__(512) void k_ss(
        const float* __restrict__ tc,
        const float* __restrict__ apw1, const float* __restrict__ apb1,
        const float* __restrict__ apw2, const float* __restrict__ apb2,
        float* __restrict__ ss1, float* __restrict__ ss2) {
    int n = blockIdx.x, b = blockIdx.y, which = blockIdx.z;
    const float* apw = which ? apw2 : apw1;
    const float* apb = which ? apb2 : apb1;
    float* ss = which ? ss2 : ss1;
    __shared__ float tcl[256];
    int tid = threadIdx.x;
    if (tid < 256) tcl[tid] = tc[b * 256 + tid];
    __syncthreads();
    float acc = apb[n * 512 + tid];
    const float* w = apw + (size_t)n * 256 * 512 + tid;
    #pragma unroll 8
    for (int k = 0; k < 256; ++k) acc += tcl[k] * w[(size_t)k * 512];
    ss[(size_t)(n * BB + b) * 512 + tid] = acc;
}

// ---------------- h init ----------------------------------------------------
__global__ __launch_bounds__(256) void k_init_h(
        const float* __restrict__ rots, const float* __restrict__ trans,
        const float* __restrict__ single,
        const float* __restrict__ frame_w, const float* __restrict__ frame_b,
        const float* __restrict__ single_w, const float* __restrict__ single_b,
        float* __restrict__ h) {
    int row = blockIdx.x;
    int tid = threadIdx.x;
    __shared__ float ff[12];
    __shared__ float sr[256];
    if (tid < 9) ff[tid] = rots[(size_t)row * 9 + tid];
    else if (tid < 12) ff[tid] = trans[(size_t)row * 3 + (tid - 9)];
    sr[tid] = single[(size_t)row * 256 + tid];
    __syncthreads();
    float acc = frame_b[tid] + single_b[tid];
    #pragma unroll
    for (int k = 0; k < 12; ++k) acc += ff[k] * frame_w[k * 256 + tid];
    #pragma unroll 8
    for (int k = 0; k < 256; ++k) acc += sr[k] * single_w[k * 256 + tid];
    h[(size_t)row * 256 + tid] = acc;
}

// ---------------- adaln layernorm (fp32 out — fallback path) ----------------
__global__ __launch_bounds__(256) void k_adaln(
        const float* __restrict__ h, const float* __restrict__ g,
        const float* __restrict__ beta, const float* __restrict__ ss,
        float* __restrict__ out) {
    int row = blockIdx.x;
    int b = row / LL;
    int tid = threadIdx.x;
    float x = h[(size_t)row * 256 + tid];
    float s = x, sq = x * x;
    #pragma unroll
    for (int off = 32; off > 0; off >>= 1) {
        s  += __shfl_down(s,  off, 64);
        sq += __shfl_down(sq, off, 64);
    }
    __shared__ float red[8];
    int wave = tid >> 6, lane = tid & 63;
    if (lane == 0) { red[wave] = s; red[4 + wave] = sq; }
    __syncthreads();
    if (tid == 0) {
        float ts = red[0] + red[1] + red[2] + red[3];
        float tq = red[4] + red[5] + red[6] + red[7];
        float mu = ts * (1.0f / 256.0f);
        float var = tq * (1.0f / 256.0f) - mu * mu;
        red[0] = mu;
        red[1] = rsqrtf(var + 1e-5f);
    }
    __syncthreads();
    float mu = red[0], inv = red[1];
    float ln = (x - mu) * inv * g[tid] + beta[tid];
    float scale = ss[b * 512 + tid];
    float shift = ss[b * 512 + 256 + tid];
    out[(size_t)row * 256 + tid] = ln * (1.0f + scale) + shift;
}

// ---------------- adaln layernorm, bf16 out ---------------------------------
__global__ __launch_bounds__(256) void k_adaln_bf(
        const float* __restrict__ h, const float* __restrict__ g,
        const float* __restrict__ beta, const float* __restrict__ ss,
        ushort_t* __restrict__ out) {
    int row = blockIdx.x;
    int b = row / LL;
    int tid = threadIdx.x;
    float x = h[(size_t)row * 256 + tid];
    float s = x, sq = x * x;
    #pragma unroll
    for (int off = 32; off > 0; off >>= 1) {
        s  += __shfl_down(s,  off, 64);
        sq += __shfl_down(sq, off, 64);
    }
    __shared__ float red[8];
    int wave = tid >> 6, lane = tid & 63;
    if (lane == 0) { red[wave] = s; red[4 + wave] = sq; }
    __syncthreads();
    if (tid == 0) {
        float ts = red[0] + red[1] + red[2] + red[3];
        float tq = red[4] + red[5] + red[6] + red[7];
        float mu = ts * (1.0f / 256.0f);
        float var = tq * (1.0f / 256.0f) - mu * mu;
        red[0] = mu;
        red[1] = rsqrtf(var + 1e-5f);
    }
    __syncthreads();
    float mu = red[0], inv = red[1];
    float ln = (x - mu) * inv * g[tid] + beta[tid];
    float scale = ss[b * 512 + tid];
    float shift = ss[b * 512 + 256 + tid];
    out[(size_t)row * 256 + tid] = f2bf(ln * (1.0f + scale) + shift);
}

// ---------------- weight convert + transpose to bf16 B^T layout -------------
// dst[n][k] = (bf16) src[k][n]
__global__ __launch_bounds__(256) void k_wt(
        const float* __restrict__ wq, const float* __restrict__ wk,
        const float* __restrict__ wv, const float* __restrict__ wo,
        const float* __restrict__ fw1, const float* __restrict__ fw2,
        ushort_t* __restrict__ wqkv_bt, ushort_t* __restrict__ wo_bt,
        ushort_t* __restrict__ fw1_bt, ushort_t* __restrict__ fw2_bt) {
    int type = blockIdx.z, nb = blockIdx.y, idx = blockIdx.x;
    int K, N; const float* src; ushort_t* dst;
    switch (type) {
        case 0: K = 256; N = 256;  src = wq  + (size_t)nb * 65536;  dst = wqkv_bt + (size_t)nb * 196608;           break;
        case 1: K = 256; N = 256;  src = wk  + (size_t)nb * 65536;  dst = wqkv_bt + (size_t)nb * 196608 + 65536;   break;
        case 2: K = 256; N = 256;  src = wv  + (size_t)nb * 65536;  dst = wqkv_bt + (size_t)nb * 196608 + 131072;  break;
        case 3: K = 256; N = 256;  src = wo  + (size_t)nb * 65536;  dst = wo_bt  + (size_t)nb * 65536;             break;
        case 4: K = 256; N = 1024; src = fw1 + (size_t)nb * 262144; dst = fw1_bt + (size_t)nb * 262144;            break;
        default:K = 1024; N = 256; src = fw2 + (size_t)nb * 262144; dst = fw2_bt + (size_t)nb * 262144;            break;
    }
    int tilesN = N >> 6;
    int tiles = (K >> 6) * tilesN;
    if (idx >= tiles) return;
    int k0 = (idx / tilesN) * 64, n0 = (idx % tilesN) * 64;
    __shared__ float lds[64][65];
    int tn = threadIdx.x & 63, tk = threadIdx.x >> 6;
    #pragma unroll
    for (int r = 0; r < 16; ++r) {
        int kk = tk + 4 * r;
        lds[kk][tn] = src[(size_t)(k0 + kk) * N + n0 + tn];
    }
    __syncthreads();
    #pragma unroll
    for (int r = 0; r < 16; ++r) {
        int nn = tk + 4 * r;
        dst[(size_t)(n0 + nn) * K + k0 + tn] = f2bf(lds[tn][nn]);
    }
}

// ---------------- MFMA bf16 GEMM: 64x64 block tile, 4 waves -----------------
// C[m][n] = sum_k A[m][k] * Wt[n][k].  A bf16 [M][K], Wt bf16 [N][K].
// MODE 0: write bf16 q/k row-major + V transposed vt[b][h][d][L] (N=768)
// MODE 1: + bias + resid -> fp32 out (N=256)
// MODE 2: + bias, gelu -> bf16 out (N=1024)
template<int KSTEPS, int MODE>
__global__ __launch_bounds__(256) void k_mfma(
        const ushort_t* __restrict__ A, const ushort_t* __restrict__ Wt,
        const float* __restrict__ bias, const float* __restrict__ resid,
        float* __restrict__ outf, ushort_t* __restrict__ outb,
        ushort_t* __restrict__ qo, ushort_t* __restrict__ ko,
        ushort_t* __restrict__ vo) {
    const int K = KSTEPS * 32;
    int m0 = blockIdx.x * 64, n0 = blockIdx.y * 64;
    int t = threadIdx.x;
    int wave = t >> 6, lane = t & 63, quad = lane >> 4, l16 = lane & 15;
    const bf16x8* Ap = (const bf16x8*)(A + (size_t)(m0 + wave * 16 + l16) * K + quad * 8);
    const bf16x8* Wp = (const bf16x8*)(Wt + (size_t)(n0 + l16) * K + quad * 8);
    const int wstride = 2 * K;  // 16 rows of Wt in bf16x8 units
    f32x4 acc[4];
    #pragma unroll
    for (int nt = 0; nt < 4; ++nt) acc[nt] = f32x4{0.f, 0.f, 0.f, 0.f};

    #pragma unroll
    for (int ks = 0; ks < KSTEPS; ++ks) {
        bf16x8 av = Ap[ks * 4];
        #pragma unroll
        for (int nt = 0; nt < 4; ++nt) {
            bf16x8 bv = Wp[nt * wstride + ks * 4];
            acc[nt] = __builtin_amdgcn_mfma_f32_16x16x32_bf16(av, bv, acc[nt], 0, 0, 0);
        }
    }

    int row_base = m0 + wave * 16 + quad * 4;
    #pragma unroll
    for (int nt = 0; nt < 4; ++nt) {
        int n = n0 + nt * 16 + l16;
        #pragma unroll
        for (int r = 0; r < 4; ++r) {
            int row = row_base + r;
            float val = acc[nt][r];
            if (MODE == 0) {
                if (n < 512) {
                    ushort_t* dst = (n < 256) ? qo : ko;
                    dst[(size_t)row * 256 + (n & 255)] = f2bf(val);
                } else {
                    int d = n & 31, hd = (n >> 5) & 7;
                    int bb = (row >= LL) ? 1 : 0;
                    int i = row - bb * LL;
                    vo[(((size_t)(bb * NH + hd)) * 32 + d) * LL + i] = f2bf(val);
                }
            } else if (MODE == 1) {
                val += bias[n] + resid[(size_t)row * 256 + n];
                outf[(size_t)row * 256 + n] = val;
            } else {
                val = gelu_exact(val + bias[n]);
                outb[(size_t)row * 1024 + n] = f2bf(val);
            }
        }
    }
}

// ---------------- generic tiled GEMM (fallback path) ------------------------
template<int NCOL, int KCH>
__global__ __launch_bounds__(256) void k_gemm4(
        const float* __restrict__ A, const float* __restrict__ W,
        const float* __restrict__ bias, const float* __restrict__ resid,
        float* __restrict__ out, int flags) {
    const int N = 256 * NCOL;
    const int K = 256 * KCH;
    int row0 = blockIdx.x * 4;
    int tid = threadIdx.x;
    __shared__ float a_s[4][256];
    float acc[4][NCOL];
    #pragma unroll
    for (int r = 0; r < 4; ++r)
        #pragma unroll
        for (int m = 0; m < NCOL; ++m) acc[r][m] = 0.f;

    for (int kc = 0; kc < KCH; ++kc) {
        if (kc) __syncthreads();
        {
            int r = tid >> 6, c4 = tid & 63;
            float4 av = reinterpret_cast<const float4*>(
                A + (size_t)(row0 + r) * K + kc * 256)[c4];
            *reinterpret_cast<float4*>(&a_s[r][c4 * 4]) = av;
        }
        __syncthreads();
        const float* Wp = W + (size_t)kc * 256 * N + tid;
        #pragma unroll 4
        for (int k = 0; k < 256; ++k) {
            float bv[NCOL];
            #pragma unroll
            for (int m = 0; m < NCOL; ++m) bv[m] = Wp[(size_t)k * N + 256 * m];
            #pragma unroll
            for (int r = 0; r < 4; ++r) {
                float a = a_s[r][k];
                #pragma unroll
                for (int m = 0; m < NCOL; ++m) acc[r][m] += a * bv[m];
            }
        }
    }
    #pragma unroll
    for (int r = 0; r < 4; ++r) {
        int row = row0 + r;
        #pragma unroll
        for (int m = 0; m < NCOL; ++m) {
            int col = tid + 256 * m;
            float v = acc[r][m];
            if (flags & 1) v += bias[col];
            if (flags & 2) v = gelu_exact(v);
            if (flags & 4) v += resid[(size_t)row * N + col];
            out[(size_t)row * N + col] = v;
        }
    }
}

// ---------------- fused QKV GEMM (fallback) ---------------------------------
__global__ __launch_bounds__(256) void k_gemm_qkv(
        const float* __restrict__ A,
        const float* __restrict__ Wq, const float* __restrict__ Wk,
        const float* __restrict__ Wv,
        float* __restrict__ q, float* __restrict__ k_,
        float* __restrict__ v) {
    int row0 = blockIdx.x * 4;
    int tid = threadIdx.x;
    __shared__ float a_s[4][256];
    {
        int r = tid >> 6, c4 = tid & 63;
        float4 av = reinterpret_cast<const float4*>(
            A + (size_t)(row0 + r) * 256)[c4];
        *reinterpret_cast<float4*>(&a_s[r][c4 * 4]) = av;
    }
    __syncthreads();
    float aq[4] = {0,0,0,0}, ak[4] = {0,0,0,0}, av_[4] = {0,0,0,0};
    #pragma unroll 4
    for (int k = 0; k < 256; ++k) {
        float wq_ = Wq[(size_t)k * 256 + tid];
        float wk_ = Wk[(size_t)k * 256 + tid];
        float wv_ = Wv[(size_t)k * 256 + tid];
        #pragma unroll
        for (int r = 0; r < 4; ++r) {
            float a = a_s[r][k];
            aq[r]  += a * wq_;
            ak[r]  += a * wk_;
            av_[r] += a * wv_;
        }
    }
    #pragma unroll
    for (int r = 0; r < 4; ++r) {
        size_t o = (size_t)(row0 + r) * 256 + tid;
        q[o] = aq[r]; k_[o] = ak[r]; v[o] = av_[r];
    }
}

// ---------------- pair bias precompute: pb[b][n*8+h][i][j] ------------------
__global__ __launch_bounds__(256) void k_pairbias(
        const float* __restrict__ pair, const float* __restrict__ pw,
        float* __restrict__ pb) {
    int row = blockIdx.x;            // b*768 + i
    int b = row / LL, i = row % LL;
    int tid = threadIdx.x;
    int j = blockIdx.y * 256 + tid;
    __shared__ float pw_t[2048];     // [nh][c] transposed
    #pragma unroll
    for (int x = 0; x < 8; ++x) {
        int idx = tid + 256 * x;
        int nh = idx >> 6, c = idx & 63;
        pw_t[idx] = pw[(nh >> 3) * 512 + c * 8 + (nh & 7)];
    }
    __syncthreads();
    float pr[64];
    {
        const float4* p4 = reinterpret_cast<const float4*>(
            pair + ((size_t)row * LL + j) * CZ);
        #pragma unroll
        for (int x = 0; x < 16; ++x) {
            float4 t4 = p4[x];
            pr[4*x] = t4.x; pr[4*x+1] = t4.y; pr[4*x+2] = t4.z; pr[4*x+3] = t4.w;
        }
    }
    #pragma unroll 4
    for (int nh = 0; nh < 32; ++nh) {
        const float4* wr = reinterpret_cast<const float4*>(&pw_t[nh * 64]);
        float s0 = 0.f, s1 = 0.f, s2 = 0.f, s3 = 0.f;
        #pragma unroll
        for (int c4 = 0; c4 < 16; ++c4) {
            float4 wv = wr[c4];
            s0 += pr[4*c4]   * wv.x;
            s1 += pr[4*c4+1] * wv.y;
            s2 += pr[4*c4+2] * wv.z;
            s3 += pr[4*c4+3] * wv.w;
        }
        pb[(((size_t)(b * 32 + nh)) * LL + i) * LL + j] = (s0 + s1) + (s2 + s3);
    }
}

// ---------------- MFMA flash attention --------------------------------------
// grid: (24 q-tiles of 32, NH, BB). block 256 = 4 waves.
// wave w: qsub = w&1 (16 q rows), jhalf = w>>1 (384 j each).
// Non-swapped QK: acc col = j (l16), row = q (quad*4+r) -> pb reads coalesced,
// softmax state per (quad,r) row, O rescale lane-local.
// P transposed via per-wave LDS bounce, split hi/lo bf16 (exact P).
__global__ __launch_bounds__(256) void k_attn_mfma(
        const ushort_t* __restrict__ qb, const ushort_t* __restrict__ kb,
        const ushort_t* __restrict__ vt, const float* __restrict__ pb,
        int n, ushort_t* __restrict__ outp) {
    int it = blockIdx.x, h = blockIdx.y, b = blockIdx.z;
    int i0 = it * 32;
    int t = threadIdx.x;
    int wave = t >> 6, lane = t & 63, quad = lane >> 4, l16 = lane & 15;
    int qsub = wave & 1, jhalf = wave >> 1;

    __shared__ __align__(16) ushort_t Plds[4][2][16][40]; // [wave][hi/lo][q][j pad40]
    __shared__ float mbuf[2][2][16];   // [qsub][jhalf][q]
    __shared__ float lbuf[2][2][16];
    __shared__ float obuf[2][2][16][33];

    // Q fragment (A operand): m-row = q (l16), k = d (quad*8..)
    bf16x8 qfrag = *(const bf16x8*)(
        qb + ((size_t)(b * LL + i0 + qsub * 16 + l16)) * 256 + h * 32 + quad * 8);

    f32x4 O0 = {0.f,0.f,0.f,0.f}, O1 = {0.f,0.f,0.f,0.f};
    float mr[4] = {-1e30f,-1e30f,-1e30f,-1e30f};
    float lr[4] = {0.f,0.f,0.f,0.f};

    const float scale = 0.17677669529663687f; // 1/sqrt(32)
    const int jbase = jhalf * 384;
    const ushort_t* kp = kb + ((size_t)(b * LL + jbase)) * 256 + h * 32 + quad * 8;
    const ushort_t* vp = vt + (((size_t)(b * NH + h)) * 32 + l16) * LL + jbase + quad * 8;
    const float* pbp = pb
        + (((size_t)(b * 32 + n * NH + h)) * LL + (i0 + qsub * 16 + quad * 4)) * LL
        + jbase + l16;

    for (int jt = 0; jt < 12; ++jt) {
        int j0 = jt * 32;
        // ---- QK^T for 32 j ----
        bf16x8 kf0 = *(const bf16x8*)(kp + (size_t)(j0 + l16) * 256);
        bf16x8 kf1 = *(const bf16x8*)(kp + (size_t)(j0 + 16 + l16) * 256);
        f32x4 s0 = __builtin_amdgcn_mfma_f32_16x16x32_bf16(qfrag, kf0, (f32x4){0.f,0.f,0.f,0.f}, 0, 0, 0);
        f32x4 s1 = __builtin_amdgcn_mfma_f32_16x16x32_bf16(qfrag, kf1, (f32x4){0.f,0.f,0.f,0.f}, 0, 0, 0);
        // ---- scale + pair bias ----
        #pragma unroll
        for (int r = 0; r < 4; ++r) {
            float b0 = pbp[(size_t)r * LL + j0];
            float b1 = pbp[(size_t)r * LL + j0 + 16];
            s0[r] = s0[r] * scale + b0;
            s1[r] = s1[r] * scale + b1;
        }
        // ---- tile row-max (reduce over 16 lanes of the quad group) ----
        float tmax[4];
        #pragma unroll
        for (int r = 0; r < 4; ++r) tmax[r] = fmaxf(s0[r], s1[r]);
        #pragma unroll
        for (int mk = 1; mk <= 8; mk <<= 1) {
            #pragma unroll
            for (int r = 0; r < 4; ++r)
                tmax[r] = fmaxf(tmax[r], __shfl_xor(tmax[r], mk, 64));
        }
        // ---- online rescale ----
        #pragma unroll
        for (int r = 0; r < 4; ++r) {
            float mn = fmaxf(mr[r], tmax[r]);
            float c = __expf(mr[r] - mn);
            mr[r] = mn;
            lr[r] *= c;
            O0[r] *= c;
            O1[r] *= c;
        }
        // ---- P = exp(s - m), row sums ----
        float p0[4], p1[4], rs[4];
        #pragma unroll
        for (int r = 0; r < 4; ++r) {
            p0[r] = __expf(s0[r] - mr[r]);
            p1[r] = __expf(s1[r] - mr[r]);
            rs[r] = p0[r] + p1[r];
        }
        #pragma unroll
        for (int mk = 1; mk <= 8; mk <<= 1) {
            #pragma unroll
            for (int r = 0; r < 4; ++r)
                rs[r] += __shfl_xor(rs[r], mk, 64);
        }
        #pragma unroll
        for (int r = 0; r < 4; ++r) lr[r] += rs[r];
        // ---- transpose P via LDS, hi/lo bf16 split ----
        #pragma unroll
        for (int r = 0; r < 4; ++r) {
            int qr = quad * 4 + r;
            ushort_t h0 = f2bf(p0[r]);
            ushort_t h1 = f2bf(p1[r]);
            Plds[wave][0][qr][l16]      = h0;
            Plds[wave][0][qr][16 + l16] = h1;
            Plds[wave][1][qr][l16]      = f2bf(p0[r] - bf2f(h0));
            Plds[wave][1][qr][16 + l16] = f2bf(p1[r] - bf2f(h1));
        }
        asm volatile("" ::: "memory");
        bf16x8 pfh = *(const bf16x8*)&Plds[wave][0][l16][quad * 8];
        bf16x8 pfl = *(const bf16x8*)&Plds[wave][1][l16][quad * 8];
        asm volatile("" ::: "memory");
        // ---- PV: O[q][d] += P[q][j] * V[j][d]; B-frag rows = d (vt) ----
        bf16x8 vf0 = *(const bf16x8*)(vp + j0);
        bf16x8 vf1 = *(const bf16x8*)(vp + (size_t)16 * LL + j0);
        O0 = __builtin_amdgcn_mfma_f32_16x16x32_bf16(pfh, vf0, O0, 0, 0, 0);
        O0 = __builtin_amdgcn_mfma_f32_16x16x32_bf16(pfl, vf0, O0, 0, 0, 0);
        O1 = __builtin_amdgcn_mfma_f32_16x16x32_bf16(pfh, vf1, O1, 0, 0, 0);
        O1 = __builtin_amdgcn_mfma_f32_16x16x32_bf16(pfl, vf1, O1, 0, 0, 0);
    }

    // ---- cross-wave (jhalf) combine ----
    if (l16 == 0) {
        #pragma unroll
        for (int r = 0; r < 4; ++r) {
            mbuf[qsub][jhalf][quad * 4 + r] = mr[r];
            lbuf[qsub][jhalf][quad * 4 + r] = lr[r];
        }
    }
    #pragma unroll
    for (int r = 0; r < 4; ++r) {
        obuf[qsub][jhalf][quad * 4 + r][l16]      = O0[r];
        obuf[qsub][jhalf][quad * 4 + r][16 + l16] = O1[r];
    }
    __syncthreads();

    {
        int q = t >> 3;            // 0..31
        int qs = q >> 4, ql = q & 15;
        int d0 = (t & 7) * 4;
        float m0 = mbuf[qs][0][ql], m1 = mbuf[qs][1][ql];
        float M = fmaxf(m0, m1);
        float w0 = __expf(m0 - M), w1 = __expf(m1 - M);
        float lt = lbuf[qs][0][ql] * w0 + lbuf[qs][1][ql] * w1;
        float inv = 1.0f / lt;
        ushort4 o4;
        o4.x = f2bf((obuf[qs][0][ql][d0+0]*w0 + obuf[qs][1][ql][d0+0]*w1) * inv);
        o4.y = f2bf((obuf[qs][0][ql][d0+1]*w0 + obuf[qs][1][ql][d0+1]*w1) * inv);
        o4.z = f2bf((obuf[qs][0][ql][d0+2]*w0 + obuf[qs][1][ql][d0+2]*w1) * inv);
        o4.w = f2bf((obuf[qs][0][ql][d0+3]*w0 + obuf[qs][1][ql][d0+3]*w1) * inv);
        *reinterpret_cast<ushort4*>(
            outp + ((size_t)(b * LL + i0 + q)) * 256 + h * 32 + d0) = o4;
    }
}

// ---------------- fallback fused attention (fp32 out) -----------------------
__global__ __launch_bounds__(256) void k_attn(
        const float* __restrict__ q, const float* __restrict__ kk,
        const float* __restrict__ v, const float* __restrict__ pair,
        const float* __restrict__ pw, float* __restrict__ outp) {
    int blk = blockIdx.x;
    int b = blk / LL, i = blk % LL;
    int tid = threadIdx.x;
    __shared__ float q_s[256];
    __shared__ float pw_s[CZ * NH];
    __shared__ float lg[NH][LL];
    __shared__ float part[8][256];
    __shared__ float invs[NH];
    size_t rowq = (size_t)(b * LL + i) * 256;
    q_s[tid] = q[rowq + tid];
    pw_s[tid] = pw[tid];
    pw_s[tid + 256] = pw[tid + 256];
    __syncthreads();

    const float scale = 0.17677669529663687f;
    for (int j = tid; j < LL; j += 256) {
        const float4* k4 = reinterpret_cast<const float4*>(kk + (size_t)(b * LL + j) * 256);
        const float4* q4 = reinterpret_cast<const float4*>(q_s);
        float dot[NH];
        #pragma unroll
        for (int h = 0; h < NH; ++h) {
            float sx = 0.f, sy = 0.f, sz = 0.f, sw = 0.f;
            #pragma unroll
            for (int dd = 0; dd < 8; ++dd) {
                float4 kv = k4[h * 8 + dd];
                float4 qv = q4[h * 8 + dd];
                sx += qv.x * kv.x; sy += qv.y * kv.y;
                sz += qv.z * kv.z; sw += qv.w * kv.w;
            }
            dot[h] = (sx + sy) + (sz + sw);
        }
        const float4* p4 = reinterpret_cast<const float4*>(
            pair + ((size_t)(b * LL + i) * LL + j) * CZ);
        float bias[NH];
        #pragma unroll
        for (int h = 0; h < NH; ++h) bias[h] = 0.f;
        #pragma unroll
        for (int c4 = 0; c4 < 16; ++c4) {
            float4 pv = p4[c4];
            int c = c4 * 4;
            #pragma unroll
            for (int h = 0; h < NH; ++h)
                bias[h] += pv.x * pw_s[(c + 0) * NH + h] + pv.y * pw_s[(c + 1) * NH + h]
                         + pv.z * pw_s[(c + 2) * NH + h] + pv.w * pw_s[(c + 3) * NH + h];
        }
        #pragma unroll
        for (int h = 0; h < NH; ++h) lg[h][j] = dot[h] * scale + bias[h];
    }
    __syncthreads();

    int wave = tid >> 6, lane = tid & 63;
    for (int h = wave; h < NH; h += 4) {
        float mx = -1e30f;
        for (int j = lane; j < LL; j += 64) mx = fmaxf(mx, lg[h][j]);
        #pragma unroll
        for (int off = 32; off > 0; off >>= 1) mx = fmaxf(mx, __shfl_xor(mx, off, 64));
        float sm = 0.f;
        for (int j = lane; j < LL; j += 64) {
            float e = __expf(lg[h][j] - mx);
            lg[h][j] = e;
            sm += e;
        }
        #pragma unroll
        for (int off = 32; off > 0; off >>= 1) sm += __shfl_xor(sm, off, 64);
        if (lane == 0) invs[h] = 1.0f / sm;
    }
    __syncthreads();

    int g = tid >> 5, d = tid & 31;
    float acc[NH];
    #pragma unroll
    for (int h = 0; h < NH; ++h) acc[h] = 0.f;
    for (int j = g; j < LL; j += 8) {
        const float* vr = v + (size_t)(b * LL + j) * 256;
        #pragma unroll
        for (int h = 0; h < NH; ++h) acc[h] += lg[h][j] * vr[h * 32 + d];
    }
    #pragma unroll
    for (int h = 0; h < NH; ++h) part[g][h * 32 + d] = acc[h];
    __syncthreads();
    float sum = 0.f;
    #pragma unroll
    for (int g2 = 0; g2 < 8; ++g2) sum += part[g2][tid];
    outp[rowq + tid] = sum * invs[tid >> 5];
}

// ---------------- final frame update ---------------------------------------
__global__ __launch_bounds__(256) void k_final(
        const float* __restrict__ h, const float* __restrict__ out_w,
        const float* __restrict__ out_b, const float* __restrict__ rots,
        const float* __restrict__ trans, float* __restrict__ out) {
    __shared__ float w_s[256 * 6];
    for (int i = threadIdx.x; i < 1536; i += 256) w_s[i] = out_w[i];
    __syncthreads();
    int row = blockIdx.x * 256 + threadIdx.x;
    if (row >= BL) return;
    const float* hr = h + (size_t)row * 256;
    float corr[6];
    #pragma unroll
    for (int c = 0; c < 6; ++c) corr[c] = out_b[c];
    for (int k = 0; k < 256; ++k) {
        float hv = hr[k];
        #pragma unroll
        for (int c = 0; c < 6; ++c) corr[c] += hv * w_s[k * 6 + c];
    }
    float vx = corr[0], vy = corr[1], vz = corr[2];
    float n = sqrtf(vx * vx + vy * vy + vz * vz);
    float inv = 1.0f / (n + 1e-8f);
    float ax = vx * inv, ay = vy * inv, az = vz * inv;
    float s = sinf(n), cc = 1.0f - cosf(n);
    float K[9] = {0.f, -az, ay,  az, 0.f, -ax,  -ay, ax, 0.f};
    float K2[9];
    #pragma unroll
    for (int ii = 0; ii < 3; ++ii)
        #pragma unroll
        for (int jj = 0; jj < 3; ++jj)
            K2[ii * 3 + jj] = K[ii * 3 + 0] * K[0 * 3 + jj]
                            + K[ii * 3 + 1] * K[1 * 3 + jj]
                            + K[ii * 3 + 2] * K[2 * 3 + jj];
    float R[9];
    #pragma unroll
    for (int ii = 0; ii < 3; ++ii)
        #pragma unroll
        for (int jj = 0; jj < 3; ++jj)
            R[ii * 3 + jj] = (ii == jj ? 1.0f : 0.0f) + s * K[ii * 3 + jj] + cc * K2[ii * 3 + jj];
    const float* ro = rots + (size_t)row * 9;
    float* o = out + (size_t)row * 12;
    #pragma unroll
    for (int ii = 0; ii < 3; ++ii)
        #pragma unroll
        for (int jj = 0; jj < 3; ++jj)
            o[ii * 3 + jj] = ro[ii * 3 + 0] * R[0 * 3 + jj]
                           + ro[ii * 3 + 1] * R[1 * 3 + jj]
                           + ro[ii * 3 + 2] * R[2 * 3 + jj];
    float t0 = corr[3], t1 = corr[4], t2 = corr[5];
    const float* tr = trans + (size_t)row * 3;
    #pragma unroll
    for (int ii = 0; ii < 3; ++ii)
        o[9 + ii] = ro[ii * 3 + 0] * t0 + ro[ii * 3 + 1] * t1 + ro[ii * 3 + 2] * t2 + tr[ii];
}

extern "C" void kernel_launch(void* const* d_in, const int* in_sizes, int n_in,
                              void* d_out, int out_size, void* d_ws, size_t ws_size,
                              hipStream_t stream) {
    (void)in_sizes; (void)n_in; (void)out_size;
    const float* rots     = (const float*)d_in[0];
    const float* trans    = (const float*)d_in[1];
    const float* t        = (const float*)d_in[2];
    const float* single   = (const float*)d_in[3];
    const float* pair     = (const float*)d_in[4];
    const float* frame_w  = (const float*)d_in[5];
    const float* frame_b  = (const float*)d_in[6];
    const float* single_w = (const float*)d_in[7];
    const float* single_b = (const float*)d_in[8];
    const float* tw1      = (const float*)d_in[9];
    const float* tb1      = (const float*)d_in[10];
    const float* tw2      = (const float*)d_in[11];
    const float* tb2      = (const float*)d_in[12];
    const float* out_w    = (const float*)d_in[13];
    const float* out_b    = (const float*)d_in[14];
    const float* ag1      = (const float*)d_in[15];
    const float* abeta1   = (const float*)d_in[16];
    const float* apw1     = (const float*)d_in[17];
    const float* apb1     = (const float*)d_in[18];
    const float* wq       = (const float*)d_in[19];
    const float* wk       = (const float*)d_in[20];
    const float* wv       = (const float*)d_in[21];
    const float* pw       = (const float*)d_in[22];
    const float* wo       = (const float*)d_in[23];
    const float* wob      = (const float*)d_in[24];
    const float* ag2      = (const float*)d_in[25];
    const float* abeta2   = (const float*)d_in[26];
    const float* apw2     = (const float*)d_in[27];
    const float* apb2     = (const float*)d_in[28];
    const float* fw1      = (const float*)d_in[29];
    const float* fb1      = (const float*)d_in[30];
    const float* fw2      = (const float*)d_in[31];
    const float* fb2      = (const float*)d_in[32];

    float* ws = (float*)d_ws;
    float* time_cond = ws;                    // 512
    float* ss1 = time_cond + 512;             // 4096
    float* ss2 = ss1 + 4096;                  // 4096
    float* h   = ss2 + 4096;                  // 393216
    float* hh  = h + 393216;                  // (fallback only)
    float* q   = hh + 393216;
    float* k_  = q + 393216;
    float* v   = k_ + 393216;
    float* attnout = v + 393216;              // (fallback only)
    float* mid = attnout + 393216;            // 1572864 (fallback only)
    float* pb  = mid + 1572864;               // 37748736 floats (151 MB)

    const size_t base_floats = 3940864ull;
    const size_t pb_floats = 37748736ull;
    ushort_t* us = (ushort_t*)(ws + base_floats + pb_floats);
    ushort_t* hh_bf      = us;                 // 393216
    ushort_t* attnout_bf = hh_bf + 393216;     // 393216
    ushort_t* mid_bf     = attnout_bf + 393216;// 1572864
    ushort_t* wqkv_bt    = mid_bf + 1572864;   // 786432
    ushort_t* wo_bt      = wqkv_bt + 786432;   // 262144
    ushort_t* fw1_bt     = wo_bt + 262144;     // 1048576
    ushort_t* fw2_bt     = fw1_bt + 1048576;   // 1048576
    const size_t us_count = 5505024ull;

    // bf16 attention operand buffers alias the (now unused in big path) fp32 q/k/v
    ushort_t* qb  = (ushort_t*)q;              // [1536][256] bf16
    ushort_t* kbb = (ushort_t*)k_;             // [1536][256] bf16
    ushort_t* vtb = (ushort_t*)v;              // [2][8][32][768] bf16 (V^T)

    const size_t need = (base_floats + pb_floats) * 4ull + us_count * 2ull;
    const bool big = ws_size >= need;

    k_time<<<BB, 256, 0, stream>>>(t, tw1, tb1, tw2, tb2, time_cond);
    k_ss<<<dim3(NBLK, BB, 2), 512, 0, stream>>>(time_cond, apw1, apb1, apw2, apb2, ss1, ss2);
    k_init_h<<<BL, 256, 0, stream>>>(rots, trans, single, frame_w, frame_b,
                                     single_w, single_b, h);
    if (big) {
        k_wt<<<dim3(64, NBLK, 6), 256, 0, stream>>>(wq, wk, wv, wo, fw1, fw2,
                                                    wqkv_bt, wo_bt, fw1_bt, fw2_bt);
        k_pairbias<<<dim3(BL, 3), 256, 0, stream>>>(pair, pw, pb);
        for (int n = 0; n < NBLK; ++n) {
            k_adaln_bf<<<BL, 256, 0, stream>>>(h, ag1 + n * 256, abeta1 + n * 256,
                                               ss1 + (size_t)n * BB * 512, hh_bf);
            k_mfma<8, 0><<<dim3(24, 12), 256, 0, stream>>>(
                hh_bf, wqkv_bt + (size_t)n * 196608, nullptr, nullptr,
                nullptr, nullptr, qb, kbb, vtb);
            k_attn_mfma<<<dim3(24, NH, BB), 256, 0, stream>>>(
                qb, kbb, vtb, pb, n, attnout_bf);
            k_mfma<8, 1><<<dim3(24, 4), 256, 0, stream>>>(
                attnout_bf, wo_bt + (size_t)n * 65536, wob + n * 256, h,
                h, nullptr, nullptr, nullptr, nullptr);
            k_adaln_bf<<<BL, 256, 0, stream>>>(h, ag2 + n * 256, abeta2 + n * 256,
                                               ss2 + (size_t)n * BB * 512, hh_bf);
            k_mfma<8, 2><<<dim3(24, 16), 256, 0, stream>>>(
                hh_bf, fw1_bt + (size_t)n * 262144, fb1 + n * 1024, nullptr,
                nullptr, mid_bf, nullptr, nullptr, nullptr);
            k_mfma<32, 1><<<dim3(24, 4), 256, 0, stream>>>(
                mid_bf, fw2_bt + (size_t)n * 262144, fb2 + n * 256, h,
                h, nullptr, nullptr, nullptr, nullptr);
        }
    } else {
        for (int n = 0; n < NBLK; ++n) {
            k_adaln<<<BL, 256, 0, stream>>>(h, ag1 + n * 256, abeta1 + n * 256,
                                            ss1 + (size_t)n * BB * 512, hh);
            k_gemm_qkv<<<BL / 4, 256, 0, stream>>>(hh, wq + (size_t)n * 65536,
                                                   wk + (size_t)n * 65536,
                                                   wv + (size_t)n * 65536, q, k_, v);
            k_attn<<<BL, 256, 0, stream>>>(q, k_, v, pair, pw + n * 512, attnout);
            k_gemm4<1, 1><<<BL / 4, 256, 0, stream>>>(attnout, wo + (size_t)n * 65536,
                                                      wob + n * 256, h, h, 1 | 4);
            k_adaln<<<BL, 256, 0, stream>>>(h, ag2 + n * 256, abeta2 + n * 256,
                                            ss2 + (size_t)n * BB * 512, hh);
            k_gemm4<4, 1><<<BL / 4, 256, 0, stream>>>(hh, fw1 + (size_t)n * 262144,
                                                      fb1 + n * 1024, nullptr, mid, 1 | 2);
            k_gemm4<1, 4><<<BL / 4, 256, 0, stream>>>(mid, fw2 + (size_t)n * 262144,
                                                      fb2 + n * 256, h, h, 1 | 4);
        }
    }
    k_final<<<6, 256, 0, stream>>>(h, out_w, out_b, rots, trans, (float*)d_out);
}

// Round 2
// 884.677 us; speedup vs baseline: 1.4327x; 1.1876x over previous
//
#include <hip/hip_runtime.h>
#include <math.h>

#define BB 2
#define LL 768
#define CC 256
#define CZ 64
#define NH 8
#define NBLK 4
#define HD 32
#define BL (BB*LL)   // 1536

typedef unsigned short ushort_t;
typedef float f32x4 __attribute__((ext_vector_type(4)));
typedef __bf16 bf16x8 __attribute__((ext_vector_type(8)));

__device__ __forceinline__ float gelu_exact(float x) {
    return 0.5f * x * (1.0f + erff(x * 0.70710678118654752f));
}

__device__ __forceinline__ ushort_t f2bf(float f) {
    union { float f; unsigned u; } x; x.f = f;
    unsigned r = x.u + 0x7fffu + ((x.u >> 16) & 1u);
    return (ushort_t)(r >> 16);
}

__device__ __forceinline__ float bf2f(ushort_t u) {
    union { unsigned u; float f; } x; x.u = ((unsigned)u) << 16;
    return x.f;
}

// ---------------- time embedding chain --------------------------------------
// pre: temb + zero tmid/time_cond; t1: tmid += temb@tw1 (k-chunked atomics);
// gelu: tmid = gelu(tmid+tb1); t2: time_cond = tb2 + tmid@tw2 (k-chunked).
__global__ __launch_bounds__(512) void k_time_pre(
        const float* __restrict__ t, float* __restrict__ temb,
        float* __restrict__ tmid, float* __restrict__ time_cond) {
    int tid = threadIdx.x;
    int b = tid >> 8, idx = tid & 255;
    int fi = idx & 127;
    float f = expf(-logf(10000.0f) * (float)fi / 128.0f);
    float a = t[b] * f;
    temb[b * 256 + idx] = (idx < 128) ? cosf(a) : sinf(a);
    #pragma unroll
    for (int e = 0; e < 4; ++e) tmid[tid + 512 * e] = 0.f;
    time_cond[tid] = 0.f;
}

__global__ __launch_bounds__(256) void k_time1(
        const float* __restrict__ temb, const float* __restrict__ tw1,
        float* __restrict__ tmid) {
    int kc = blockIdx.x, b = blockIdx.y;   // grid (8, BB), 32 k per chunk
    int tid = threadIdx.x;
    __shared__ float te[32];
    if (tid < 32) te[tid] = temb[b * 256 + kc * 32 + tid];
    __syncthreads();
    float acc[4] = {0.f, 0.f, 0.f, 0.f};
    #pragma unroll
    for (int k = 0; k < 32; ++k) {
        const float* wr = tw1 + (size_t)(kc * 32 + k) * 1024;
        float tv = te[k];
        #pragma unroll
        for (int m = 0; m < 4; ++m) acc[m] += tv * wr[tid + 256 * m];
    }
    #pragma unroll
    for (int m = 0; m < 4; ++m) atomicAdd(&tmid[b * 1024 + tid + 256 * m], acc[m]);
}

__global__ __launch_bounds__(512) void k_time_gelu(
        float* __restrict__ tmid, const float* __restrict__ tb1) {
    int tid = threadIdx.x;
    #pragma unroll
    for (int e = 0; e < 4; ++e) {
        int i = tid + 512 * e;
        tmid[i] = gelu_exact(tmid[i] + tb1[i & 1023]);
    }
}

__global__ __launch_bounds__(256) void k_time2(
        const float* __restrict__ tmid, const float* __restrict__ tw2,
        const float* __restrict__ tb2, float* __restrict__ time_cond) {
    int kc = blockIdx.x, b = blockIdx.y;   // grid (16, BB), 64 k per chunk
    int tid = threadIdx.x;
    __shared__ float mg[64];
    if (tid < 64) mg[tid] = tmid[b * 1024 + kc * 64 + tid];
    __syncthreads();
    float acc = (kc == 0) ? tb2[tid] : 0.f;
    #pragma unroll
    for (int k = 0; k < 64; ++k)
        acc += mg[k] * tw2[(size_t)(kc * 64 + k) * 256 + tid];
    atomicAdd(&time_cond[b * 256 + tid], acc);
}

// ---------------- adaln scale/shift tables ---------------------------------
__global__ __launch_bounds__(512) void k_ss(
        const float* __restrict__ tc,
        const float* __restrict__ apw1, const float* __restrict__ apb1,
        const float* __restrict__ apw2, const float* __restrict__ apb2,
        float* __restrict__ ss1, float* __restrict__ ss2) {
    int n = blockIdx.x, b = blockIdx.y, which = blockIdx.z;
    const float* apw = which ? apw2 : apw1;
    const float* apb = which ? apb2 : apb1;
    float* ss = which ? ss2 : ss1;
    __shared__ float tcl[256];
    int tid = threadIdx.x;
    if (tid < 256) tcl[tid] = tc[b * 256 + tid];
    __syncthreads();
    float acc = apb[n * 512 + tid];
    const float* w = apw + (size_t)n * 256 * 512 + tid;
    #pragma unroll 8
    for (int k = 0; k < 256; ++k) acc += tcl[k] * w[(size_t)k * 512];
    ss[(size_t)(n * BB + b) * 512 + tid] = acc;
}

// ---------------- h init ----------------------------------------------------
__global__ __launch_bounds__(256) void k_init_h(
        const float* __restrict__ rots, const float* __restrict__ trans,
        const float* __restrict__ single,
        const float* __restrict__ frame_w, const float* __restrict__ frame_b,
        const float* __restrict__ single_w, const float* __restrict__ single_b,
        float* __restrict__ h) {
    int row = blockIdx.x;
    int tid = threadIdx.x;
    __shared__ float ff[12];
    __shared__ float sr[256];
    if (tid < 9) ff[tid] = rots[(size_t)row * 9 + tid];
    else if (tid < 12) ff[tid] = trans[(size_t)row * 3 + (tid - 9)];
    sr[tid] = single[(size_t)row * 256 + tid];
    __syncthreads();
    float acc = frame_b[tid] + single_b[tid];
    #pragma unroll
    for (int k = 0; k < 12; ++k) acc += ff[k] * frame_w[k * 256 + tid];
    #pragma unroll 8
    for (int k = 0; k < 256; ++k) acc += sr[k] * single_w[k * 256 + tid];
    h[(size_t)row * 256 + tid] = acc;
}

// ---------------- adaln layernorm (fp32 out — fallback path) ----------------
__global__ __launch_bounds__(256) void k_adaln(
        const float* __restrict__ h, const float* __restrict__ g,
        const float* __restrict__ beta, const float* __restrict__ ss,
        float* __restrict__ out) {
    int row = blockIdx.x;
    int b = row / LL;
    int tid = threadIdx.x;
    float x = h[(size_t)row * 256 + tid];
    float s = x, sq = x * x;
    #pragma unroll
    for (int off = 32; off > 0; off >>= 1) {
        s  += __shfl_down(s,  off, 64);
        sq += __shfl_down(sq, off, 64);
    }
    __shared__ float red[8];
    int wave = tid >> 6, lane = tid & 63;
    if (lane == 0) { red[wave] = s; red[4 + wave] = sq; }
    __syncthreads();
    if (tid == 0) {
        float ts = red[0] + red[1] + red[2] + red[3];
        float tq = red[4] + red[5] + red[6] + red[7];
        float mu = ts * (1.0f / 256.0f);
        float var = tq * (1.0f / 256.0f) - mu * mu;
        red[0] = mu;
        red[1] = rsqrtf(var + 1e-5f);
    }
    __syncthreads();
    float mu = red[0], inv = red[1];
    float ln = (x - mu) * inv * g[tid] + beta[tid];
    float scale = ss[b * 512 + tid];
    float shift = ss[b * 512 + 256 + tid];
    out[(size_t)row * 256 + tid] = ln * (1.0f + scale) + shift;
}

// ---------------- adaln layernorm, bf16 out ---------------------------------
__global__ __launch_bounds__(256) void k_adaln_bf(
        const float* __restrict__ h, const float* __restrict__ g,
        const float* __restrict__ beta, const float* __restrict__ ss,
        ushort_t* __restrict__ out) {
    int row = blockIdx.x;
    int b = row / LL;
    int tid = threadIdx.x;
    float x = h[(size_t)row * 256 + tid];
    float s = x, sq = x * x;
    #pragma unroll
    for (int off = 32; off > 0; off >>= 1) {
        s  += __shfl_down(s,  off, 64);
        sq += __shfl_down(sq, off, 64);
    }
    __shared__ float red[8];
    int wave = tid >> 6, lane = tid & 63;
    if (lane == 0) { red[wave] = s; red[4 + wave] = sq; }
    __syncthreads();
    if (tid == 0) {
        float ts = red[0] + red[1] + red[2] + red[3];
        float tq = red[4] + red[5] + red[6] + red[7];
        float mu = ts * (1.0f / 256.0f);
        float var = tq * (1.0f / 256.0f) - mu * mu;
        red[0] = mu;
        red[1] = rsqrtf(var + 1e-5f);
    }
    __syncthreads();
    float mu = red[0], inv = red[1];
    float ln = (x - mu) * inv * g[tid] + beta[tid];
    float scale = ss[b * 512 + tid];
    float shift = ss[b * 512 + 256 + tid];
    out[(size_t)row * 256 + tid] = f2bf(ln * (1.0f + scale) + shift);
}

// ---------------- weight convert + transpose to bf16 B^T layout -------------
// dst[n][k] = (bf16) src[k][n]
__global__ __launch_bounds__(256) void k_wt(
        const float* __restrict__ wq, const float* __restrict__ wk,
        const float* __restrict__ wv, const float* __restrict__ wo,
        const float* __restrict__ fw1, const float* __restrict__ fw2,
        ushort_t* __restrict__ wqkv_bt, ushort_t* __restrict__ wo_bt,
        ushort_t* __restrict__ fw1_bt, ushort_t* __restrict__ fw2_bt) {
    int type = blockIdx.z, nb = blockIdx.y, idx = blockIdx.x;
    int K, N; const float* src; ushort_t* dst;
    switch (type) {
        case 0: K = 256; N = 256;  src = wq  + (size_t)nb * 65536;  dst = wqkv_bt + (size_t)nb * 196608;           break;
        case 1: K = 256; N = 256;  src = wk  + (size_t)nb * 65536;  dst = wqkv_bt + (size_t)nb * 196608 + 65536;   break;
        case 2: K = 256; N = 256;  src = wv  + (size_t)nb * 65536;  dst = wqkv_bt + (size_t)nb * 196608 + 131072;  break;
        case 3: K = 256; N = 256;  src = wo  + (size_t)nb * 65536;  dst = wo_bt  + (size_t)nb * 65536;             break;
        case 4: K = 256; N = 1024; src = fw1 + (size_t)nb * 262144; dst = fw1_bt + (size_t)nb * 262144;            break;
        default:K = 1024; N = 256; src = fw2 + (size_t)nb * 262144; dst = fw2_bt + (size_t)nb * 262144;            break;
    }
    int tilesN = N >> 6;
    int tiles = (K >> 6) * tilesN;
    if (idx >= tiles) return;
    int k0 = (idx / tilesN) * 64, n0 = (idx % tilesN) * 64;
    __shared__ float lds[64][65];
    int tn = threadIdx.x & 63, tk = threadIdx.x >> 6;
    #pragma unroll
    for (int r = 0; r < 16; ++r) {
        int kk = tk + 4 * r;
        lds[kk][tn] = src[(size_t)(k0 + kk) * N + n0 + tn];
    }
    __syncthreads();
    #pragma unroll
    for (int r = 0; r < 16; ++r) {
        int nn = tk + 4 * r;
        dst[(size_t)(n0 + nn) * K + k0 + tn] = f2bf(lds[tn][nn]);
    }
}

// ---------------- MFMA bf16 GEMM: 64x64 block tile, 4 waves -----------------
// C[m][n] = sum_k A[m][k] * Wt[n][k].  A bf16 [M][K], Wt bf16 [N][K].
// MODE 0: write bf16 q/k row-major + V transposed vt[b][h][d][L] (N=768)
// MODE 2: + bias, gelu -> bf16 out (N=1024)
template<int KSTEPS, int MODE>
__global__ __launch_bounds__(256) void k_mfma(
        const ushort_t* __restrict__ A, const ushort_t* __restrict__ Wt,
        const float* __restrict__ bias, const float* __restrict__ resid,
        float* __restrict__ outf, ushort_t* __restrict__ outb,
        ushort_t* __restrict__ qo, ushort_t* __restrict__ ko,
        ushort_t* __restrict__ vo) {
    const int K = KSTEPS * 32;
    int m0 = blockIdx.x * 64, n0 = blockIdx.y * 64;
    int t = threadIdx.x;
    int wave = t >> 6, lane = t & 63, quad = lane >> 4, l16 = lane & 15;
    const bf16x8* Ap = (const bf16x8*)(A + (size_t)(m0 + wave * 16 + l16) * K + quad * 8);
    const bf16x8* Wp = (const bf16x8*)(Wt + (size_t)(n0 + l16) * K + quad * 8);
    const int wstride = 2 * K;  // 16 rows of Wt in bf16x8 units
    f32x4 acc[4];
    #pragma unroll
    for (int nt = 0; nt < 4; ++nt) acc[nt] = f32x4{0.f, 0.f, 0.f, 0.f};

    #pragma unroll
    for (int ks = 0; ks < KSTEPS; ++ks) {
        bf16x8 av = Ap[ks * 4];
        #pragma unroll
        for (int nt = 0; nt < 4; ++nt) {
            bf16x8 bv = Wp[nt * wstride + ks * 4];
            acc[nt] = __builtin_amdgcn_mfma_f32_16x16x32_bf16(av, bv, acc[nt], 0, 0, 0);
        }
    }

    int row_base = m0 + wave * 16 + quad * 4;
    #pragma unroll
    for (int nt = 0; nt < 4; ++nt) {
        int n = n0 + nt * 16 + l16;
        #pragma unroll
        for (int r = 0; r < 4; ++r) {
            int row = row_base + r;
            float val = acc[nt][r];
            if (MODE == 0) {
                if (n < 512) {
                    ushort_t* dst = (n < 256) ? qo : ko;
                    dst[(size_t)row * 256 + (n & 255)] = f2bf(val);
                } else {
                    int d = n & 31, hd = (n >> 5) & 7;
                    int bb = (row >= LL) ? 1 : 0;
                    int i = row - bb * LL;
                    vo[(((size_t)(bb * NH + hd)) * 32 + d) * LL + i] = f2bf(val);
                }
            } else if (MODE == 1) {
                val += bias[n] + resid[(size_t)row * 256 + n];
                outf[(size_t)row * 256 + n] = val;
            } else {
                val = gelu_exact(val + bias[n]);
                outb[(size_t)row * 1024 + n] = f2bf(val);
            }
        }
    }
}

// ---------------- MFMA bf16 GEMM: 32x32 tile, 1 wave per 16x16 --------------
// bias + resid -> fp32 out.  Grid (M/32, N/32), 384 blocks for M=1536,N=256.
template<int KSTEPS>
__global__ __launch_bounds__(256) void k_mfma32(
        const ushort_t* __restrict__ A, const ushort_t* __restrict__ Wt,
        const float* __restrict__ bias, const float* __restrict__ resid,
        float* __restrict__ outf) {
    const int K = KSTEPS * 32;
    int m0 = blockIdx.x * 32, n0 = blockIdx.y * 32;
    int t = threadIdx.x;
    int wave = t >> 6, lane = t & 63, quad = lane >> 4, l16 = lane & 15;
    int msub = wave & 1, nsub = wave >> 1;
    const bf16x8* Ap = (const bf16x8*)(A + (size_t)(m0 + msub * 16 + l16) * K + quad * 8);
    const bf16x8* Wp = (const bf16x8*)(Wt + (size_t)(n0 + nsub * 16 + l16) * K + quad * 8);
    f32x4 acc = {0.f, 0.f, 0.f, 0.f};
    #pragma unroll 8
    for (int ks = 0; ks < KSTEPS; ++ks)
        acc = __builtin_amdgcn_mfma_f32_16x16x32_bf16(Ap[ks * 4], Wp[ks * 4], acc, 0, 0, 0);
    int n = n0 + nsub * 16 + l16;
    int row0 = m0 + msub * 16 + quad * 4;
    float bv = bias[n];
    #pragma unroll
    for (int r = 0; r < 4; ++r) {
        int row = row0 + r;
        outf[(size_t)row * 256 + n] = acc[r] + bv + resid[(size_t)row * 256 + n];
    }
}

// ---------------- generic tiled GEMM (fallback path) ------------------------
template<int NCOL, int KCH>
__global__ __launch_bounds__(256) void k_gemm4(
        const float* __restrict__ A, const float* __restrict__ W,
        const float* __restrict__ bias, const float* __restrict__ resid,
        float* __restrict__ out, int flags) {
    const int N = 256 * NCOL;
    const int K = 256 * KCH;
    int row0 = blockIdx.x * 4;
    int tid = threadIdx.x;
    __shared__ float a_s[4][256];
    float acc[4][NCOL];
    #pragma unroll
    for (int r = 0; r < 4; ++r)
        #pragma unroll
        for (int m = 0; m < NCOL; ++m) acc[r][m] = 0.f;

    for (int kc = 0; kc < KCH; ++kc) {
        if (kc) __syncthreads();
        {
            int r = tid >> 6, c4 = tid & 63;
            float4 av = reinterpret_cast<const float4*>(
                A + (size_t)(row0 + r) * K + kc * 256)[c4];
            *reinterpret_cast<float4*>(&a_s[r][c4 * 4]) = av;
        }
        __syncthreads();
        const float* Wp = W + (size_t)kc * 256 * N + tid;
        #pragma unroll 4
        for (int k = 0; k < 256; ++k) {
            float bv[NCOL];
            #pragma unroll
            for (int m = 0; m < NCOL; ++m) bv[m] = Wp[(size_t)k * N + 256 * m];
            #pragma unroll
            for (int r = 0; r < 4; ++r) {
                float a = a_s[r][k];
                #pragma unroll
                for (int m = 0; m < NCOL; ++m) acc[r][m] += a * bv[m];
            }
        }
    }
    #pragma unroll
    for (int r = 0; r < 4; ++r) {
        int row = row0 + r;
        #pragma unroll
        for (int m = 0; m < NCOL; ++m) {
            int col = tid + 256 * m;
            float v = acc[r][m];
            if (flags & 1) v += bias[col];
            if (flags & 2) v = gelu_exact(v);
            if (flags & 4) v += resid[(size_t)row * N + col];
            out[(size_t)row * N + col] = v;
        }
    }
}

// ---------------- fused QKV GEMM (fallback) ---------------------------------
__global__ __launch_bounds__(256) void k_gemm_qkv(
        const float* __restrict__ A,
        const float* __restrict__ Wq, const float* __restrict__ Wk,
        const float* __restrict__ Wv,
        float* __restrict__ q, float* __restrict__ k_,
        float* __restrict__ v) {
    int row0 = blockIdx.x * 4;
    int tid = threadIdx.x;
    __shared__ float a_s[4][256];
    {
        int r = tid >> 6, c4 = tid & 63;
        float4 av = reinterpret_cast<const float4*>(
            A + (size_t)(row0 + r) * 256)[c4];
        *reinterpret_cast<float4*>(&a_s[r][c4 * 4]) = av;
    }
    __syncthreads();
    float aq[4] = {0,0,0,0}, ak[4] = {0,0,0,0}, av_[4] = {0,0,0,0};
    #pragma unroll 4
    for (int k = 0; k < 256; ++k) {
        float wq_ = Wq[(size_t)k * 256 + tid];
        float wk_ = Wk[(size_t)k * 256 + tid];
        float wv_ = Wv[(size_t)k * 256 + tid];
        #pragma unroll
        for (int r = 0; r < 4; ++r) {
            float a = a_s[r][k];
            aq[r]  += a * wq_;
            ak[r]  += a * wk_;
            av_[r] += a * wv_;
        }
    }
    #pragma unroll
    for (int r = 0; r < 4; ++r) {
        size_t o = (size_t)(row0 + r) * 256 + tid;
        q[o] = aq[r]; k_[o] = ak[r]; v[o] = av_[r];
    }
}

// ---------------- pair bias via MFMA (hi/lo bf16, 3-term ~= fp32) -----------
// pb[b][nh][i][j] = sum_c pair[b,i,j,c] * pw[nh>>3][c][nh&7]
// One block per (b,i).  4 waves x 12 j-tiles of 16.  No LDS.
__global__ __launch_bounds__(256) void k_pairbias(
        const float* __restrict__ pair, const float* __restrict__ pw,
        float* __restrict__ pb) {
    int row = blockIdx.x;            // b*768 + i
    int b = row / LL, i = row % LL;
    int t = threadIdx.x;
    int wave = t >> 6, lane = t & 63, quad = lane >> 4, l16 = lane & 15;

    // B fragments: lane l16 = nh within tile; quad*8 = c offset
    bf16x8 Bhi[2][2], Blo[2][2];
    #pragma unroll
    for (int tt = 0; tt < 2; ++tt) {
        int nh = tt * 16 + l16;
        int n = nh >> 3, hh = nh & 7;
        #pragma unroll
        for (int ks = 0; ks < 2; ++ks) {
            #pragma unroll
            for (int e = 0; e < 8; ++e) {
                int c = ks * 32 + quad * 8 + e;
                float w = pw[n * 512 + c * 8 + hh];
                __bf16 hi = (__bf16)w;
                float lo = w - (float)hi;
                Bhi[tt][ks][e] = hi;
                Blo[tt][ks][e] = (__bf16)lo;
            }
        }
    }

    const float* prow = pair + (size_t)row * LL * CZ;
    for (int x = 0; x < 12; ++x) {
        int j0 = (wave + 4 * x) * 16;
        bf16x8 Ahi[2], Alo[2];
        #pragma unroll
        for (int ks = 0; ks < 2; ++ks) {
            const float4* src = reinterpret_cast<const float4*>(
                prow + (size_t)(j0 + l16) * CZ + ks * 32 + quad * 8);
            float4 v0 = src[0], v1 = src[1];
            float f[8] = {v0.x, v0.y, v0.z, v0.w, v1.x, v1.y, v1.z, v1.w};
            #pragma unroll
            for (int e = 0; e < 8; ++e) {
                __bf16 hi = (__bf16)f[e];
                Ahi[ks][e] = hi;
                Alo[ks][e] = (__bf16)(f[e] - (float)hi);
            }
        }
        #pragma unroll
        for (int tt = 0; tt < 2; ++tt) {
            f32x4 acc = {0.f, 0.f, 0.f, 0.f};
            #pragma unroll
            for (int ks = 0; ks < 2; ++ks) {
                acc = __builtin_amdgcn_mfma_f32_16x16x32_bf16(Ahi[ks], Bhi[tt][ks], acc, 0, 0, 0);
                acc = __builtin_amdgcn_mfma_f32_16x16x32_bf16(Alo[ks], Bhi[tt][ks], acc, 0, 0, 0);
                acc = __builtin_amdgcn_mfma_f32_16x16x32_bf16(Ahi[ks], Blo[tt][ks], acc, 0, 0, 0);
            }
            int nh = tt * 16 + l16;
            float4 o = make_float4(acc[0], acc[1], acc[2], acc[3]);
            *reinterpret_cast<float4*>(
                pb + (((size_t)(b * 32 + nh)) * LL + i) * LL + j0 + quad * 4) = o;
        }
    }
}

// ---------------- MFMA flash attention --------------------------------------
__global__ __launch_bounds__(256) void k_attn_mfma(
        const ushort_t* __restrict__ qb, const ushort_t* __restrict__ kb,
        const ushort_t* __restrict__ vt, const float* __restrict__ pb,
        int n, ushort_t* __restrict__ outp) {
    int it = blockIdx.x, h = blockIdx.y, b = blockIdx.z;
    int i0 = it * 32;
    int t = threadIdx.x;
    int wave = t >> 6, lane = t & 63, quad = lane >> 4, l16 = lane & 15;
    int qsub = wave & 1, jhalf = wave >> 1;

    __shared__ __align__(16) ushort_t Plds[4][2][16][40]; // [wave][hi/lo][q][j pad40]
    __shared__ float mbuf[2][2][16];   // [qsub][jhalf][q]
    __shared__ float lbuf[2][2][16];
    __shared__ float obuf[2][2][16][33];

    bf16x8 qfrag = *(const bf16x8*)(
        qb + ((size_t)(b * LL + i0 + qsub * 16 + l16)) * 256 + h * 32 + quad * 8);

    f32x4 O0 = {0.f,0.f,0.f,0.f}, O1 = {0.f,0.f,0.f,0.f};
    float mr[4] = {-1e30f,-1e30f,-1e30f,-1e30f};
    float lr[4] = {0.f,0.f,0.f,0.f};

    const float scale = 0.17677669529663687f; // 1/sqrt(32)
    const int jbase = jhalf * 384;
    const ushort_t* kp = kb + ((size_t)(b * LL + jbase)) * 256 + h * 32 + quad * 8;
    const ushort_t* vp = vt + (((size_t)(b * NH + h)) * 32 + l16) * LL + jbase + quad * 8;
    const float* pbp = pb
        + (((size_t)(b * 32 + n * NH + h)) * LL + (i0 + qsub * 16 + quad * 4)) * LL
        + jbase + l16;

    for (int jt = 0; jt < 12; ++jt) {
        int j0 = jt * 32;
        bf16x8 kf0 = *(const bf16x8*)(kp + (size_t)(j0 + l16) * 256);
        bf16x8 kf1 = *(const bf16x8*)(kp + (size_t)(j0 + 16 + l16) * 256);
        f32x4 s0 = __builtin_amdgcn_mfma_f32_16x16x32_bf16(qfrag, kf0, (f32x4){0.f,0.f,0.f,0.f}, 0, 0, 0);
        f32x4 s1 = __builtin_amdgcn_mfma_f32_16x16x32_bf16(qfrag, kf1, (f32x4){0.f,0.f,0.f,0.f}, 0, 0, 0);
        #pragma unroll
        for (int r = 0; r < 4; ++r) {
            float b0 = pbp[(size_t)r * LL + j0];
            float b1 = pbp[(size_t)r * LL + j0 + 16];
            s0[r] = s0[r] * scale + b0;
            s1[r] = s1[r] * scale + b1;
        }
        float tmax[4];
        #pragma unroll
        for (int r = 0; r < 4; ++r) tmax[r] = fmaxf(s0[r], s1[r]);
        #pragma unroll
        for (int mk = 1; mk <= 8; mk <<= 1) {
            #pragma unroll
            for (int r = 0; r < 4; ++r)
                tmax[r] = fmaxf(tmax[r], __shfl_xor(tmax[r], mk, 64));
        }
        #pragma unroll
        for (int r = 0; r < 4; ++r) {
            float mn = fmaxf(mr[r], tmax[r]);
            float c = __expf(mr[r] - mn);
            mr[r] = mn;
            lr[r] *= c;
            O0[r] *= c;
            O1[r] *= c;
        }
        float p0[4], p1[4], rs[4];
        #pragma unroll
        for (int r = 0; r < 4; ++r) {
            p0[r] = __expf(s0[r] - mr[r]);
            p1[r] = __expf(s1[r] - mr[r]);
            rs[r] = p0[r] + p1[r];
        }
        #pragma unroll
        for (int mk = 1; mk <= 8; mk <<= 1) {
            #pragma unroll
            for (int r = 0; r < 4; ++r)
                rs[r] += __shfl_xor(rs[r], mk, 64);
        }
        #pragma unroll
        for (int r = 0; r < 4; ++r) lr[r] += rs[r];
        #pragma unroll
        for (int r = 0; r < 4; ++r) {
            int qr = quad * 4 + r;
            ushort_t h0 = f2bf(p0[r]);
            ushort_t h1 = f2bf(p1[r]);
            Plds[wave][0][qr][l16]      = h0;
            Plds[wave][0][qr][16 + l16] = h1;
            Plds[wave][1][qr][l16]      = f2bf(p0[r] - bf2f(h0));
            Plds[wave][1][qr][16 + l16] = f2bf(p1[r] - bf2f(h1));
        }
        asm volatile("" ::: "memory");
        bf16x8 pfh = *(const bf16x8*)&Plds[wave][0][l16][quad * 8];
        bf16x8 pfl = *(const bf16x8*)&Plds[wave][1][l16][quad * 8];
        asm volatile("" ::: "memory");
        bf16x8 vf0 = *(const bf16x8*)(vp + j0);
        bf16x8 vf1 = *(const bf16x8*)(vp + (size_t)16 * LL + j0);
        O0 = __builtin_amdgcn_mfma_f32_16x16x32_bf16(pfh, vf0, O0, 0, 0, 0);
        O0 = __builtin_amdgcn_mfma_f32_16x16x32_bf16(pfl, vf0, O0, 0, 0, 0);
        O1 = __builtin_amdgcn_mfma_f32_16x16x32_bf16(pfh, vf1, O1, 0, 0, 0);
        O1 = __builtin_amdgcn_mfma_f32_16x16x32_bf16(pfl, vf1, O1, 0, 0, 0);
    }

    if (l16 == 0) {
        #pragma unroll
        for (int r = 0; r < 4; ++r) {
            mbuf[qsub][jhalf][quad * 4 + r] = mr[r];
            lbuf[qsub][jhalf][quad * 4 + r] = lr[r];
        }
    }
    #pragma unroll
    for (int r = 0; r < 4; ++r) {
        obuf[qsub][jhalf][quad * 4 + r][l16]      = O0[r];
        obuf[qsub][jhalf][quad * 4 + r][16 + l16] = O1[r];
    }
    __syncthreads();

    {
        int q = t >> 3;            // 0..31
        int qs = q >> 4, ql = q & 15;
        int d0 = (t & 7) * 4;
        float m0 = mbuf[qs][0][ql], m1 = mbuf[qs][1][ql];
        float M = fmaxf(m0, m1);
        float w0 = __expf(m0 - M), w1 = __expf(m1 - M);
        float lt = lbuf[qs][0][ql] * w0 + lbuf[qs][1][ql] * w1;
        float inv = 1.0f / lt;
        ushort4 o4;
        o4.x = f2bf((obuf[qs][0][ql][d0+0]*w0 + obuf[qs][1][ql][d0+0]*w1) * inv);
        o4.y = f2bf((obuf[qs][0][ql][d0+1]*w0 + obuf[qs][1][ql][d0+1]*w1) * inv);
        o4.z = f2bf((obuf[qs][0][ql][d0+2]*w0 + obuf[qs][1][ql][d0+2]*w1) * inv);
        o4.w = f2bf((obuf[qs][0][ql][d0+3]*w0 + obuf[qs][1][ql][d0+3]*w1) * inv);
        *reinterpret_cast<ushort4*>(
            outp + ((size_t)(b * LL + i0 + q)) * 256 + h * 32 + d0) = o4;
    }
}

// ---------------- fallback fused attention (fp32 out) -----------------------
__global__ __launch_bounds__(256) void k_attn(
        const float* __restrict__ q, const float* __restrict__ kk,
        const float* __restrict__ v, const float* __restrict__ pair,
        const float* __restrict__ pw, float* __restrict__ outp) {
    int blk = blockIdx.x;
    int b = blk / LL, i = blk % LL;
    int tid = threadIdx.x;
    __shared__ float q_s[256];
    __shared__ float pw_s[CZ * NH];
    __shared__ float lg[NH][LL];
    __shared__ float part[8][256];
    __shared__ float invs[NH];
    size_t rowq = (size_t)(b * LL + i) * 256;
    q_s[tid] = q[rowq + tid];
    pw_s[tid] = pw[tid];
    pw_s[tid + 256] = pw[tid + 256];
    __syncthreads();

    const float scale = 0.17677669529663687f;
    for (int j = tid; j < LL; j += 256) {
        const float4* k4 = reinterpret_cast<const float4*>(kk + (size_t)(b * LL + j) * 256);
        const float4* q4 = reinterpret_cast<const float4*>(q_s);
        float dot[NH];
        #pragma unroll
        for (int h = 0; h < NH; ++h) {
            float sx = 0.f, sy = 0.f, sz = 0.f, sw = 0.f;
            #pragma unroll
            for (int dd = 0; dd < 8; ++dd) {
                float4 kv = k4[h * 8 + dd];
                float4 qv = q4[h * 8 + dd];
                sx += qv.x * kv.x; sy += qv.y * kv.y;
                sz += qv.z * kv.z; sw += qv.w * kv.w;
            }
            dot[h] = (sx + sy) + (sz + sw);
        }
        const float4* p4 = reinterpret_cast<const float4*>(
            pair + ((size_t)(b * LL + i) * LL + j) * CZ);
        float bias[NH];
        #pragma unroll
        for (int h = 0; h < NH; ++h) bias[h] = 0.f;
        #pragma unroll
        for (int c4 = 0; c4 < 16; ++c4) {
            float4 pv = p4[c4];
            int c = c4 * 4;
            #pragma unroll
            for (int h = 0; h < NH; ++h)
                bias[h] += pv.x * pw_s[(c + 0) * NH + h] + pv.y * pw_s[(c + 1) * NH + h]
                         + pv.z * pw_s[(c + 2) * NH + h] + pv.w * pw_s[(c + 3) * NH + h];
        }
        #pragma unroll
        for (int h = 0; h < NH; ++h) lg[h][j] = dot[h] * scale + bias[h];
    }
    __syncthreads();

    int wave = tid >> 6, lane = tid & 63;
    for (int h = wave; h < NH; h += 4) {
        float mx = -1e30f;
        for (int j = lane; j < LL; j += 64) mx = fmaxf(mx, lg[h][j]);
        #pragma unroll
        for (int off = 32; off > 0; off >>= 1) mx = fmaxf(mx, __shfl_xor(mx, off, 64));
        float sm = 0.f;
        for (int j = lane; j < LL; j += 64) {
            float e = __expf(lg[h][j] - mx);
            lg[h][j] = e;
            sm += e;
        }
        #pragma unroll
        for (int off = 32; off > 0; off >>= 1) sm += __shfl_xor(sm, off, 64);
        if (lane == 0) invs[h] = 1.0f / sm;
    }
    __syncthreads();

    int g = tid >> 5, d = tid & 31;
    float acc[NH];
    #pragma unroll
    for (int h = 0; h < NH; ++h) acc[h] = 0.f;
    for (int j = g; j < LL; j += 8) {
        const float* vr = v + (size_t)(b * LL + j) * 256;
        #pragma unroll
        for (int h = 0; h < NH; ++h) acc[h] += lg[h][j] * vr[h * 32 + d];
    }
    #pragma unroll
    for (int h = 0; h < NH; ++h) part[g][h * 32 + d] = acc[h];
    __syncthreads();
    float sum = 0.f;
    #pragma unroll
    for (int g2 = 0; g2 < 8; ++g2) sum += part[g2][tid];
    outp[rowq + tid] = sum * invs[tid >> 5];
}

// ---------------- final frame update (wave per row) -------------------------
__global__ __launch_bounds__(256) void k_final(
        const float* __restrict__ h, const float* __restrict__ out_w,
        const float* __restrict__ out_b, const float* __restrict__ rots,
        const float* __restrict__ trans, float* __restrict__ out) {
    __shared__ float w_s[256 * 6];
    int t = threadIdx.x, wave = t >> 6, lane = t & 63;
    for (int i = t; i < 1536; i += 256) w_s[i] = out_w[i];
    __syncthreads();
    int row = blockIdx.x * 4 + wave;
    const float* hr = h + (size_t)row * 256;
    float4 hv = reinterpret_cast<const float4*>(hr)[lane];
    int k0 = lane * 4;
    float c[6];
    #pragma unroll
    for (int cc = 0; cc < 6; ++cc)
        c[cc] = hv.x * w_s[(k0+0)*6+cc] + hv.y * w_s[(k0+1)*6+cc]
              + hv.z * w_s[(k0+2)*6+cc] + hv.w * w_s[(k0+3)*6+cc];
    #pragma unroll
    for (int off = 32; off > 0; off >>= 1)
        #pragma unroll
        for (int cc = 0; cc < 6; ++cc)
            c[cc] += __shfl_xor(c[cc], off, 64);
    if (lane == 0) {
        float corr[6];
        #pragma unroll
        for (int cc = 0; cc < 6; ++cc) corr[cc] = c[cc] + out_b[cc];
        float vx = corr[0], vy = corr[1], vz = corr[2];
        float n = sqrtf(vx * vx + vy * vy + vz * vz);
        float inv = 1.0f / (n + 1e-8f);
        float ax = vx * inv, ay = vy * inv, az = vz * inv;
        float s = sinf(n), ccs = 1.0f - cosf(n);
        float K[9] = {0.f, -az, ay,  az, 0.f, -ax,  -ay, ax, 0.f};
        float K2[9];
        #pragma unroll
        for (int ii = 0; ii < 3; ++ii)
            #pragma unroll
            for (int jj = 0; jj < 3; ++jj)
                K2[ii * 3 + jj] = K[ii * 3 + 0] * K[0 * 3 + jj]
                                + K[ii * 3 + 1] * K[1 * 3 + jj]
                                + K[ii * 3 + 2] * K[2 * 3 + jj];
        float R[9];
        #pragma unroll
        for (int ii = 0; ii < 3; ++ii)
            #pragma unroll
            for (int jj = 0; jj < 3; ++jj)
                R[ii * 3 + jj] = (ii == jj ? 1.0f : 0.0f) + s * K[ii * 3 + jj] + ccs * K2[ii * 3 + jj];
        const float* ro = rots + (size_t)row * 9;
        float* o = out + (size_t)row * 12;
        #pragma unroll
        for (int ii = 0; ii < 3; ++ii)
            #pragma unroll
            for (int jj = 0; jj < 3; ++jj)
                o[ii * 3 + jj] = ro[ii * 3 + 0] * R[0 * 3 + jj]
                               + ro[ii * 3 + 1] * R[1 * 3 + jj]
                               + ro[ii * 3 + 2] * R[2 * 3 + jj];
        float t0 = corr[3], t1 = corr[4], t2 = corr[5];
        const float* tr = trans + (size_t)row * 3;
        #pragma unroll
        for (int ii = 0; ii < 3; ++ii)
            o[9 + ii] = ro[ii * 3 + 0] * t0 + ro[ii * 3 + 1] * t1 + ro[ii * 3 + 2] * t2 + tr[ii];
    }
}

extern "C" void kernel_launch(void* const* d_in, const int* in_sizes, int n_in,
                              void* d_out, int out_size, void* d_ws, size_t ws_size,
                              hipStream_t stream) {
    (void)in_sizes; (void)n_in; (void)out_size;
    const float* rots     = (const float*)d_in[0];
    const float* trans    = (const float*)d_in[1];
    const float* t        = (const float*)d_in[2];
    const float* single   = (const float*)d_in[3];
    const float* pair     = (const float*)d_in[4];
    const float* frame_w  = (const float*)d_in[5];
    const float* frame_b  = (const float*)d_in[6];
    const float* single_w = (const float*)d_in[7];
    const float* single_b = (const float*)d_in[8];
    const float* tw1      = (const float*)d_in[9];
    const float* tb1      = (const float*)d_in[10];
    const float* tw2      = (const float*)d_in[11];
    const float* tb2      = (const float*)d_in[12];
    const float* out_w    = (const float*)d_in[13];
    const float* out_b    = (const float*)d_in[14];
    const float* ag1      = (const float*)d_in[15];
    const float* abeta1   = (const float*)d_in[16];
    const float* apw1     = (const float*)d_in[17];
    const float* apb1     = (const float*)d_in[18];
    const float* wq       = (const float*)d_in[19];
    const float* wk       = (const float*)d_in[20];
    const float* wv       = (const float*)d_in[21];
    const float* pw       = (const float*)d_in[22];
    const float* wo       = (const float*)d_in[23];
    const float* wob      = (const float*)d_in[24];
    const float* ag2      = (const float*)d_in[25];
    const float* abeta2   = (const float*)d_in[26];
    const float* apw2     = (const float*)d_in[27];
    const float* apb2     = (const float*)d_in[28];
    const float* fw1      = (const float*)d_in[29];
    const float* fb1      = (const float*)d_in[30];
    const float* fw2      = (const float*)d_in[31];
    const float* fb2      = (const float*)d_in[32];

    float* ws = (float*)d_ws;
    float* time_cond = ws;                    // 512
    float* ss1 = time_cond + 512;             // 4096
    float* ss2 = ss1 + 4096;                  // 4096
    float* h   = ss2 + 4096;                  // 393216
    float* hh  = h + 393216;                  // (fallback only)
    float* q   = hh + 393216;
    float* k_  = q + 393216;
    float* v   = k_ + 393216;
    float* attnout = v + 393216;              // (fallback only)
    float* mid = attnout + 393216;            // 1572864 (fallback FFN; big: time scratch)
    float* pb  = mid + 1572864;               // 37748736 floats (151 MB)

    float* tmid    = mid;                     // 2048 (time chain scratch)
    float* temb_ws = mid + 2048;              // 512

    const size_t base_floats = 3940864ull;
    const size_t pb_floats = 37748736ull;
    ushort_t* us = (ushort_t*)(ws + base_floats + pb_floats);
    ushort_t* hh_bf      = us;                 // 393216
    ushort_t* attnout_bf = hh_bf + 393216;     // 393216
    ushort_t* mid_bf     = attnout_bf + 393216;// 1572864
    ushort_t* wqkv_bt    = mid_bf + 1572864;   // 786432
    ushort_t* wo_bt      = wqkv_bt + 786432;   // 262144
    ushort_t* fw1_bt     = wo_bt + 262144;     // 1048576
    ushort_t* fw2_bt     = fw1_bt + 1048576;   // 1048576
    const size_t us_count = 5505024ull;

    // bf16 attention operand buffers alias the (big-path-unused) fp32 q/k/v
    ushort_t* qb  = (ushort_t*)q;              // [1536][256] bf16
    ushort_t* kbb = (ushort_t*)k_;             // [1536][256] bf16
    ushort_t* vtb = (ushort_t*)v;              // [2][8][32][768] bf16 (V^T)

    const size_t need = (base_floats + pb_floats) * 4ull + us_count * 2ull;
    const bool big = ws_size >= need;

    k_time_pre<<<1, 512, 0, stream>>>(t, temb_ws, tmid, time_cond);
    k_time1<<<dim3(8, BB), 256, 0, stream>>>(temb_ws, tw1, tmid);
    k_time_gelu<<<1, 512, 0, stream>>>(tmid, tb1);
    k_time2<<<dim3(16, BB), 256, 0, stream>>>(tmid, tw2, tb2, time_cond);
    k_ss<<<dim3(NBLK, BB, 2), 512, 0, stream>>>(time_cond, apw1, apb1, apw2, apb2, ss1, ss2);
    k_init_h<<<BL, 256, 0, stream>>>(rots, trans, single, frame_w, frame_b,
                                     single_w, single_b, h);
    if (big) {
        k_wt<<<dim3(64, NBLK, 6), 256, 0, stream>>>(wq, wk, wv, wo, fw1, fw2,
                                                    wqkv_bt, wo_bt, fw1_bt, fw2_bt);
        k_pairbias<<<BL, 256, 0, stream>>>(pair, pw, pb);
        for (int n = 0; n < NBLK; ++n) {
            k_adaln_bf<<<BL, 256, 0, stream>>>(h, ag1 + n * 256, abeta1 + n * 256,
                                               ss1 + (size_t)n * BB * 512, hh_bf);
            k_mfma<8, 0><<<dim3(24, 12), 256, 0, stream>>>(
                hh_bf, wqkv_bt + (size_t)n * 196608, nullptr, nullptr,
                nullptr, nullptr, qb, kbb, vtb);
            k_attn_mfma<<<dim3(24, NH, BB), 256, 0, stream>>>(
                qb, kbb, vtb, pb, n, attnout_bf);
            k_mfma32<8><<<dim3(48, 8), 256, 0, stream>>>(
                attnout_bf, wo_bt + (size_t)n * 65536, wob + n * 256, h, h);
            k_adaln_bf<<<BL, 256, 0, stream>>>(h, ag2 + n * 256, abeta2 + n * 256,
                                               ss2 + (size_t)n * BB * 512, hh_bf);
            k_mfma<8, 2><<<dim3(24, 16), 256, 0, stream>>>(
                hh_bf, fw1_bt + (size_t)n * 262144, fb1 + n * 1024, nullptr,
                nullptr, mid_bf, nullptr, nullptr, nullptr);
            k_mfma32<32><<<dim3(48, 8), 256, 0, stream>>>(
                mid_bf, fw2_bt + (size_t)n * 262144, fb2 + n * 256, h, h);
        }
    } else {
        for (int n = 0; n < NBLK; ++n) {
            k_adaln<<<BL, 256, 0, stream>>>(h, ag1 + n * 256, abeta1 + n * 256,
                                            ss1 + (size_t)n * BB * 512, hh);
            k_gemm_qkv<<<BL / 4, 256, 0, stream>>>(hh, wq + (size_t)n * 65536,
                                                   wk + (size_t)n * 65536,
                                                   wv + (size_t)n * 65536, q, k_, v);
            k_attn<<<BL, 256, 0, stream>>>(q, k_, v, pair, pw + n * 512, attnout);
            k_gemm4<1, 1><<<BL / 4, 256, 0, stream>>>(attnout, wo + (size_t)n * 65536,
                                                      wob + n * 256, h, h, 1 | 4);
            k_adaln<<<BL, 256, 0, stream>>>(h, ag2 + n * 256, abeta2 + n * 256,
                                            ss2 + (size_t)n * BB * 512, hh);
            k_gemm4<4, 1><<<BL / 4, 256, 0, stream>>>(hh, fw1 + (size_t)n * 262144,
                                                      fb1 + n * 1024, nullptr, mid, 1 | 2);
            k_gemm4<1, 4><<<BL / 4, 256, 0, stream>>>(mid, fw2 + (size_t)n * 262144,
                                                      fb2 + n * 256, h, h, 1 | 4);
        }
    }
    k_final<<<BL / 4, 256, 0, stream>>>(h, out_w, out_b, rots, trans, (float*)d_out);
}

// Round 3
// 807.712 us; speedup vs baseline: 1.5693x; 1.0953x over previous
//
#include <hip/hip_runtime.h>
#include <math.h>

#define BB 2
#define LL 768
#define CC 256
#define CZ 64
#define NH 8
#define NBLK 4
#define HD 32
#define BL (BB*LL)   // 1536

typedef unsigned short ushort_t;
typedef float f32x4 __attribute__((ext_vector_type(4)));
typedef __bf16 bf16x8 __attribute__((ext_vector_type(8)));
typedef ushort_t us8 __attribute__((ext_vector_type(8)));

__device__ __forceinline__ float gelu_exact(float x) {
    return 0.5f * x * (1.0f + erff(x * 0.70710678118654752f));
}

__device__ __forceinline__ ushort_t f2bf(float f) {
    union { float f; unsigned u; } x; x.f = f;
    unsigned r = x.u + 0x7fffu + ((x.u >> 16) & 1u);
    return (ushort_t)(r >> 16);
}

__device__ __forceinline__ float bf2f(ushort_t u) {
    union { unsigned u; float f; } x; x.u = ((unsigned)u) << 16;
    return x.f;
}

// ---------------- zero scratch ----------------------------------------------
__global__ __launch_bounds__(512) void k_zero(
        float* __restrict__ tmid, float* __restrict__ time_cond,
        float* __restrict__ ss1, float* __restrict__ ss2) {
    int tid = threadIdx.x;
    #pragma unroll
    for (int e = 0; e < 4; ++e) tmid[tid + 512 * e] = 0.f;
    time_cond[tid] = 0.f;
    #pragma unroll
    for (int e = 0; e < 8; ++e) {
        ss1[tid + 512 * e] = 0.f;
        ss2[tid + 512 * e] = 0.f;
    }
}

// ---------------- time chain: tmid += temb@tw1 (temb computed inline) -------
__global__ __launch_bounds__(256) void k_time1(
        const float* __restrict__ t, const float* __restrict__ tw1,
        float* __restrict__ tmid) {
    int kc = blockIdx.x, b = blockIdx.y;   // grid (8, BB), 32 k per chunk
    int tid = threadIdx.x;
    __shared__ float te[32];
    if (tid < 32) {
        int idx = kc * 32 + tid;
        int fi = idx & 127;
        float f = expf(-logf(10000.0f) * (float)fi / 128.0f);
        float a = t[b] * f;
        te[tid] = (idx < 128) ? cosf(a) : sinf(a);
    }
    __syncthreads();
    float acc[4] = {0.f, 0.f, 0.f, 0.f};
    #pragma unroll
    for (int k = 0; k < 32; ++k) {
        const float* wr = tw1 + (size_t)(kc * 32 + k) * 1024;
        float tv = te[k];
        #pragma unroll
        for (int m = 0; m < 4; ++m) acc[m] += tv * wr[tid + 256 * m];
    }
    #pragma unroll
    for (int m = 0; m < 4; ++m) atomicAdd(&tmid[b * 1024 + tid + 256 * m], acc[m]);
}

// time_cond = tb2 + gelu(tmid+tb1)@tw2  (gelu applied at load)
__global__ __launch_bounds__(256) void k_time2(
        const float* __restrict__ tmid, const float* __restrict__ tb1,
        const float* __restrict__ tw2, const float* __restrict__ tb2,
        float* __restrict__ time_cond) {
    int kc = blockIdx.x, b = blockIdx.y;   // grid (16, BB), 64 k per chunk
    int tid = threadIdx.x;
    __shared__ float mg[64];
    if (tid < 64) {
        int idx = kc * 64 + tid;
        mg[tid] = gelu_exact(tmid[b * 1024 + idx] + tb1[idx]);
    }
    __syncthreads();
    float acc = (kc == 0) ? tb2[tid] : 0.f;
    #pragma unroll
    for (int k = 0; k < 64; ++k)
        acc += mg[k] * tw2[(size_t)(kc * 64 + k) * 256 + tid];
    atomicAdd(&time_cond[b * 256 + tid], acc);
}

// ---------------- adaln scale/shift tables (k-split, atomics) ---------------
__global__ __launch_bounds__(512) void k_ss(
        const float* __restrict__ tc,
        const float* __restrict__ apw1, const float* __restrict__ apb1,
        const float* __restrict__ apw2, const float* __restrict__ apb2,
        float* __restrict__ ss1, float* __restrict__ ss2) {
    int kc = blockIdx.x & 7, n = blockIdx.x >> 3;   // grid.x = 32
    int b = blockIdx.y, which = blockIdx.z;
    const float* apw = which ? apw2 : apw1;
    const float* apb = which ? apb2 : apb1;
    float* ss = which ? ss2 : ss1;
    __shared__ float tcl[32];
    int tid = threadIdx.x;
    if (tid < 32) tcl[tid] = tc[b * 256 + kc * 32 + tid];
    __syncthreads();
    float acc = (kc == 0) ? apb[n * 512 + tid] : 0.f;
    const float* w = apw + (size_t)n * 256 * 512 + (size_t)(kc * 32) * 512 + tid;
    #pragma unroll 8
    for (int k = 0; k < 32; ++k) acc += tcl[k] * w[(size_t)k * 512];
    atomicAdd(&ss[(size_t)(n * BB + b) * 512 + tid], acc);
}

// ---------------- h init ----------------------------------------------------
__global__ __launch_bounds__(256) void k_init_h(
        const float* __restrict__ rots, const float* __restrict__ trans,
        const float* __restrict__ single,
        const float* __restrict__ frame_w, const float* __restrict__ frame_b,
        const float* __restrict__ single_w, const float* __restrict__ single_b,
        float* __restrict__ h) {
    int row = blockIdx.x;
    int tid = threadIdx.x;
    __shared__ float ff[12];
    __shared__ float sr[256];
    if (tid < 9) ff[tid] = rots[(size_t)row * 9 + tid];
    else if (tid < 12) ff[tid] = trans[(size_t)row * 3 + (tid - 9)];
    sr[tid] = single[(size_t)row * 256 + tid];
    __syncthreads();
    float acc = frame_b[tid] + single_b[tid];
    #pragma unroll
    for (int k = 0; k < 12; ++k) acc += ff[k] * frame_w[k * 256 + tid];
    #pragma unroll 8
    for (int k = 0; k < 256; ++k) acc += sr[k] * single_w[k * 256 + tid];
    h[(size_t)row * 256 + tid] = acc;
}

// ---------------- adaln layernorm (fp32 out — fallback path) ----------------
__global__ __launch_bounds__(256) void k_adaln(
        const float* __restrict__ h, const float* __restrict__ g,
        const float* __restrict__ beta, const float* __restrict__ ss,
        float* __restrict__ out) {
    int row = blockIdx.x;
    int b = row / LL;
    int tid = threadIdx.x;
    float x = h[(size_t)row * 256 + tid];
    float s = x, sq = x * x;
    #pragma unroll
    for (int off = 32; off > 0; off >>= 1) {
        s  += __shfl_down(s,  off, 64);
        sq += __shfl_down(sq, off, 64);
    }
    __shared__ float red[8];
    int wave = tid >> 6, lane = tid & 63;
    if (lane == 0) { red[wave] = s; red[4 + wave] = sq; }
    __syncthreads();
    if (tid == 0) {
        float ts = red[0] + red[1] + red[2] + red[3];
        float tq = red[4] + red[5] + red[6] + red[7];
        float mu = ts * (1.0f / 256.0f);
        float var = tq * (1.0f / 256.0f) - mu * mu;
        red[0] = mu;
        red[1] = rsqrtf(var + 1e-5f);
    }
    __syncthreads();
    float mu = red[0], inv = red[1];
    float ln = (x - mu) * inv * g[tid] + beta[tid];
    float scale = ss[b * 512 + tid];
    float shift = ss[b * 512 + 256 + tid];
    out[(size_t)row * 256 + tid] = ln * (1.0f + scale) + shift;
}

// ---------------- adaln layernorm, bf16 out ---------------------------------
__global__ __launch_bounds__(256) void k_adaln_bf(
        const float* __restrict__ h, const float* __restrict__ g,
        const float* __restrict__ beta, const float* __restrict__ ss,
        ushort_t* __restrict__ out) {
    int row = blockIdx.x;
    int b = row / LL;
    int tid = threadIdx.x;
    float x = h[(size_t)row * 256 + tid];
    float s = x, sq = x * x;
    #pragma unroll
    for (int off = 32; off > 0; off >>= 1) {
        s  += __shfl_down(s,  off, 64);
        sq += __shfl_down(sq, off, 64);
    }
    __shared__ float red[8];
    int wave = tid >> 6, lane = tid & 63;
    if (lane == 0) { red[wave] = s; red[4 + wave] = sq; }
    __syncthreads();
    if (tid == 0) {
        float ts = red[0] + red[1] + red[2] + red[3];
        float tq = red[4] + red[5] + red[6] + red[7];
        float mu = ts * (1.0f / 256.0f);
        float var = tq * (1.0f / 256.0f) - mu * mu;
        red[0] = mu;
        red[1] = rsqrtf(var + 1e-5f);
    }
    __syncthreads();
    float mu = red[0], inv = red[1];
    float ln = (x - mu) * inv * g[tid] + beta[tid];
    float scale = ss[b * 512 + tid];
    float shift = ss[b * 512 + 256 + tid];
    out[(size_t)row * 256 + tid] = f2bf(ln * (1.0f + scale) + shift);
}

// ---------------- weight convert + transpose to bf16 B^T layout -------------
__global__ __launch_bounds__(256) void k_wt(
        const float* __restrict__ wq, const float* __restrict__ wk,
        const float* __restrict__ wv, const float* __restrict__ wo,
        const float* __restrict__ fw1, const float* __restrict__ fw2,
        ushort_t* __restrict__ wqkv_bt, ushort_t* __restrict__ wo_bt,
        ushort_t* __restrict__ fw1_bt, ushort_t* __restrict__ fw2_bt) {
    int type = blockIdx.z, nb = blockIdx.y, idx = blockIdx.x;
    int K, N; const float* src; ushort_t* dst;
    switch (type) {
        case 0: K = 256; N = 256;  src = wq  + (size_t)nb * 65536;  dst = wqkv_bt + (size_t)nb * 196608;           break;
        case 1: K = 256; N = 256;  src = wk  + (size_t)nb * 65536;  dst = wqkv_bt + (size_t)nb * 196608 + 65536;   break;
        case 2: K = 256; N = 256;  src = wv  + (size_t)nb * 65536;  dst = wqkv_bt + (size_t)nb * 196608 + 131072;  break;
        case 3: K = 256; N = 256;  src = wo  + (size_t)nb * 65536;  dst = wo_bt  + (size_t)nb * 65536;             break;
        case 4: K = 256; N = 1024; src = fw1 + (size_t)nb * 262144; dst = fw1_bt + (size_t)nb * 262144;            break;
        default:K = 1024; N = 256; src = fw2 + (size_t)nb * 262144; dst = fw2_bt + (size_t)nb * 262144;            break;
    }
    int tilesN = N >> 6;
    int tiles = (K >> 6) * tilesN;
    if (idx >= tiles) return;
    int k0 = (idx / tilesN) * 64, n0 = (idx % tilesN) * 64;
    __shared__ float lds[64][65];
    int tn = threadIdx.x & 63, tk = threadIdx.x >> 6;
    #pragma unroll
    for (int r = 0; r < 16; ++r) {
        int kk = tk + 4 * r;
        lds[kk][tn] = src[(size_t)(k0 + kk) * N + n0 + tn];
    }
    __syncthreads();
    #pragma unroll
    for (int r = 0; r < 16; ++r) {
        int nn = tk + 4 * r;
        dst[(size_t)(n0 + nn) * K + k0 + tn] = f2bf(lds[tn][nn]);
    }
}

// ---------------- MFMA bf16 GEMM: 64x64 block tile, LDS-staged stores -------
// MODE 0: bf16 q/k row-major + V transposed vt[b][h][d][L]  (N=768)
// MODE 2: + bias, gelu -> bf16 out (N=1024)
template<int KSTEPS, int MODE>
__global__ __launch_bounds__(256) void k_mfma(
        const ushort_t* __restrict__ A, const ushort_t* __restrict__ Wt,
        const float* __restrict__ bias, ushort_t* __restrict__ outb,
        ushort_t* __restrict__ qo, ushort_t* __restrict__ ko,
        ushort_t* __restrict__ vo) {
    const int K = KSTEPS * 32;
    int m0 = blockIdx.x * 64, n0 = blockIdx.y * 64;
    int t = threadIdx.x;
    int wave = t >> 6, lane = t & 63, quad = lane >> 4, l16 = lane & 15;
    __shared__ ushort_t ot[64][72];
    const bf16x8* Ap = (const bf16x8*)(A + (size_t)(m0 + wave * 16 + l16) * K + quad * 8);
    const bf16x8* Wp = (const bf16x8*)(Wt + (size_t)(n0 + l16) * K + quad * 8);
    const int wstride = 2 * K;
    f32x4 acc[4];
    #pragma unroll
    for (int nt = 0; nt < 4; ++nt) acc[nt] = f32x4{0.f, 0.f, 0.f, 0.f};

    #pragma unroll
    for (int ks = 0; ks < KSTEPS; ++ks) {
        bf16x8 av = Ap[ks * 4];
        #pragma unroll
        for (int nt = 0; nt < 4; ++nt) {
            bf16x8 bv = Wp[nt * wstride + ks * 4];
            acc[nt] = __builtin_amdgcn_mfma_f32_16x16x32_bf16(av, bv, acc[nt], 0, 0, 0);
        }
    }

    int row_l = wave * 16 + quad * 4;
    #pragma unroll
    for (int nt = 0; nt < 4; ++nt) {
        int col = nt * 16 + l16;
        #pragma unroll
        for (int r = 0; r < 4; ++r) {
            float val = acc[nt][r];
            if (MODE == 2) val = gelu_exact(val + bias[n0 + col]);
            ot[row_l + r][col] = f2bf(val);
        }
    }
    __syncthreads();

    if (MODE == 2) {
        int rr = t >> 2, cc = (t & 3) * 16;
        us8 v0 = *(const us8*)&ot[rr][cc];
        us8 v1 = *(const us8*)&ot[rr][cc + 8];
        size_t o = (size_t)(m0 + rr) * 1024 + n0 + cc;
        *(us8*)&outb[o] = v0;
        *(us8*)&outb[o + 8] = v1;
    } else if (n0 < 512) {
        ushort_t* dst = (n0 < 256) ? qo : ko;
        int rr = t >> 2, cc = (t & 3) * 16;
        us8 v0 = *(const us8*)&ot[rr][cc];
        us8 v1 = *(const us8*)&ot[rr][cc + 8];
        size_t o = (size_t)(m0 + rr) * 256 + (n0 & 255) + cc;
        *(us8*)&dst[o] = v0;
        *(us8*)&dst[o + 8] = v1;
    } else {
        int dl = t >> 2, ii = (t & 3) * 16;
        int ng = n0 + dl;
        int hd = (ng >> 5) & 7, d = ng & 31;
        int bb = (m0 >= LL) ? 1 : 0;
        int ibase = m0 - bb * LL + ii;
        us8 v0, v1;
        #pragma unroll
        for (int e = 0; e < 8; ++e) v0[e] = ot[ii + e][dl];
        #pragma unroll
        for (int e = 0; e < 8; ++e) v1[e] = ot[ii + 8 + e][dl];
        size_t o = (((size_t)(bb * NH + hd)) * 32 + d) * LL + ibase;
        *(us8*)&vo[o] = v0;
        *(us8*)&vo[o + 8] = v1;
    }
}

// ---------------- MFMA bf16 GEMM: 32x32 tile, bias+resid fp32 out -----------
template<int KSTEPS>
__global__ __launch_bounds__(256) void k_mfma32(
        const ushort_t* __restrict__ A, const ushort_t* __restrict__ Wt,
        const float* __restrict__ bias, const float* __restrict__ resid,
        float* __restrict__ outf) {
    const int K = KSTEPS * 32;
    int m0 = blockIdx.x * 32, n0 = blockIdx.y * 32;
    int t = threadIdx.x;
    int wave = t >> 6, lane = t & 63, quad = lane >> 4, l16 = lane & 15;
    int msub = wave & 1, nsub = wave >> 1;
    const bf16x8* Ap = (const bf16x8*)(A + (size_t)(m0 + msub * 16 + l16) * K + quad * 8);
    const bf16x8* Wp = (const bf16x8*)(Wt + (size_t)(n0 + nsub * 16 + l16) * K + quad * 8);
    f32x4 acc = {0.f, 0.f, 0.f, 0.f};
    #pragma unroll 8
    for (int ks = 0; ks < KSTEPS; ++ks)
        acc = __builtin_amdgcn_mfma_f32_16x16x32_bf16(Ap[ks * 4], Wp[ks * 4], acc, 0, 0, 0);
    int n = n0 + nsub * 16 + l16;
    int row0 = m0 + msub * 16 + quad * 4;
    float bv = bias[n];
    #pragma unroll
    for (int r = 0; r < 4; ++r) {
        int row = row0 + r;
        outf[(size_t)row * 256 + n] = acc[r] + bv + resid[(size_t)row * 256 + n];
    }
}

// ---------------- generic tiled GEMM (fallback path) ------------------------
template<int NCOL, int KCH>
__global__ __launch_bounds__(256) void k_gemm4(
        const float* __restrict__ A, const float* __restrict__ W,
        const float* __restrict__ bias, const float* __restrict__ resid,
        float* __restrict__ out, int flags) {
    const int N = 256 * NCOL;
    const int K = 256 * KCH;
    int row0 = blockIdx.x * 4;
    int tid = threadIdx.x;
    __shared__ float a_s[4][256];
    float acc[4][NCOL];
    #pragma unroll
    for (int r = 0; r < 4; ++r)
        #pragma unroll
        for (int m = 0; m < NCOL; ++m) acc[r][m] = 0.f;

    for (int kc = 0; kc < KCH; ++kc) {
        if (kc) __syncthreads();
        {
            int r = tid >> 6, c4 = tid & 63;
            float4 av = reinterpret_cast<const float4*>(
                A + (size_t)(row0 + r) * K + kc * 256)[c4];
            *reinterpret_cast<float4*>(&a_s[r][c4 * 4]) = av;
        }
        __syncthreads();
        const float* Wp = W + (size_t)kc * 256 * N + tid;
        #pragma unroll 4
        for (int k = 0; k < 256; ++k) {
            float bv[NCOL];
            #pragma unroll
            for (int m = 0; m < NCOL; ++m) bv[m] = Wp[(size_t)k * N + 256 * m];
            #pragma unroll
            for (int r = 0; r < 4; ++r) {
                float a = a_s[r][k];
                #pragma unroll
                for (int m = 0; m < NCOL; ++m) acc[r][m] += a * bv[m];
            }
        }
    }
    #pragma unroll
    for (int r = 0; r < 4; ++r) {
        int row = row0 + r;
        #pragma unroll
        for (int m = 0; m < NCOL; ++m) {
            int col = tid + 256 * m;
            float v = acc[r][m];
            if (flags & 1) v += bias[col];
            if (flags & 2) v = gelu_exact(v);
            if (flags & 4) v += resid[(size_t)row * N + col];
            out[(size_t)row * N + col] = v;
        }
    }
}

// ---------------- fused QKV GEMM (fallback) ---------------------------------
__global__ __launch_bounds__(256) void k_gemm_qkv(
        const float* __restrict__ A,
        const float* __restrict__ Wq, const float* __restrict__ Wk,
        const float* __restrict__ Wv,
        float* __restrict__ q, float* __restrict__ k_,
        float* __restrict__ v) {
    int row0 = blockIdx.x * 4;
    int tid = threadIdx.x;
    __shared__ float a_s[4][256];
    {
        int r = tid >> 6, c4 = tid & 63;
        float4 av = reinterpret_cast<const float4*>(
            A + (size_t)(row0 + r) * 256)[c4];
        *reinterpret_cast<float4*>(&a_s[r][c4 * 4]) = av;
    }
    __syncthreads();
    float aq[4] = {0,0,0,0}, ak[4] = {0,0,0,0}, av_[4] = {0,0,0,0};
    #pragma unroll 4
    for (int k = 0; k < 256; ++k) {
        float wq_ = Wq[(size_t)k * 256 + tid];
        float wk_ = Wk[(size_t)k * 256 + tid];
        float wv_ = Wv[(size_t)k * 256 + tid];
        #pragma unroll
        for (int r = 0; r < 4; ++r) {
            float a = a_s[r][k];
            aq[r]  += a * wq_;
            ak[r]  += a * wk_;
            av_[r] += a * wv_;
        }
    }
    #pragma unroll
    for (int r = 0; r < 4; ++r) {
        size_t o = (size_t)(row0 + r) * 256 + tid;
        q[o] = aq[r]; k_[o] = ak[r]; v[o] = av_[r];
    }
}

// ---------------- pair bias via MFMA -> bf16 pb, coalesced writes -----------
// pb[b][nh][i][j] (bf16) = sum_c pair[b,i,j,c] * pw[nh>>3][c][nh&7]
__global__ __launch_bounds__(256) void k_pairbias(
        const float* __restrict__ pair, const float* __restrict__ pw,
        ushort_t* __restrict__ pb) {
    int row = blockIdx.x;            // b*768 + i
    int b = row / LL, i = row % LL;
    int t = threadIdx.x;
    int wave = t >> 6, lane = t & 63, quad = lane >> 4, l16 = lane & 15;

    __shared__ ushort_t tile[32][72];   // [nh][j-local 64, pad]

    bf16x8 Bhi[2][2], Blo[2][2];
    #pragma unroll
    for (int tt = 0; tt < 2; ++tt) {
        int nh = tt * 16 + l16;
        int n = nh >> 3, hh = nh & 7;
        #pragma unroll
        for (int ks = 0; ks < 2; ++ks) {
            #pragma unroll
            for (int e = 0; e < 8; ++e) {
                int c = ks * 32 + quad * 8 + e;
                float w = pw[n * 512 + c * 8 + hh];
                __bf16 hi = (__bf16)w;
                float lo = w - (float)hi;
                Bhi[tt][ks][e] = hi;
                Blo[tt][ks][e] = (__bf16)lo;
            }
        }
    }

    const float* prow = pair + (size_t)row * LL * CZ;
    int wnh = t >> 3, wjj = (t & 7) * 8;   // write-phase mapping
    for (int x = 0; x < 12; ++x) {
        int j0 = (4 * x + wave) * 16;
        bf16x8 Ahi[2], Alo[2];
        #pragma unroll
        for (int ks = 0; ks < 2; ++ks) {
            const float4* src = reinterpret_cast<const float4*>(
                prow + (size_t)(j0 + l16) * CZ + ks * 32 + quad * 8);
            float4 v0 = src[0], v1 = src[1];
            float f[8] = {v0.x, v0.y, v0.z, v0.w, v1.x, v1.y, v1.z, v1.w};
            #pragma unroll
            for (int e = 0; e < 8; ++e) {
                __bf16 hi = (__bf16)f[e];
                Ahi[ks][e] = hi;
                Alo[ks][e] = (__bf16)(f[e] - (float)hi);
            }
        }
        #pragma unroll
        for (int tt = 0; tt < 2; ++tt) {
            f32x4 acc = {0.f, 0.f, 0.f, 0.f};
            #pragma unroll
            for (int ks = 0; ks < 2; ++ks) {
                acc = __builtin_amdgcn_mfma_f32_16x16x32_bf16(Ahi[ks], Bhi[tt][ks], acc, 0, 0, 0);
                acc = __builtin_amdgcn_mfma_f32_16x16x32_bf16(Alo[ks], Bhi[tt][ks], acc, 0, 0, 0);
                acc = __builtin_amdgcn_mfma_f32_16x16x32_bf16(Ahi[ks], Blo[tt][ks], acc, 0, 0, 0);
            }
            int nh = tt * 16 + l16;
            int jl = wave * 16 + quad * 4;
            ushort4 st;
            st.x = f2bf(acc[0]); st.y = f2bf(acc[1]);
            st.z = f2bf(acc[2]); st.w = f2bf(acc[3]);
            *reinterpret_cast<ushort4*>(&tile[nh][jl]) = st;
        }
        __syncthreads();
        {
            us8 v = *(const us8*)&tile[wnh][wjj];
            *(us8*)&pb[(((size_t)(b * 32 + wnh)) * LL + i) * LL + 64 * x + wjj] = v;
        }
        __syncthreads();
    }
}

// ---------------- MFMA flash attention (16-q blocks, 4 j-quarter waves) -----
__global__ __launch_bounds__(256) void k_attn_mfma(
        const ushort_t* __restrict__ qb, const ushort_t* __restrict__ kb,
        const ushort_t* __restrict__ vt, const ushort_t* __restrict__ pb,
        int n, ushort_t* __restrict__ outp) {
    int it = blockIdx.x, h = blockIdx.y, b = blockIdx.z;
    int i0 = it * 16;
    int t = threadIdx.x;
    int wave = t >> 6, lane = t & 63, quad = lane >> 4, l16 = lane & 15;

    __shared__ __align__(16) ushort_t Plds[4][2][16][40];
    __shared__ float mbuf[4][16];
    __shared__ float lbuf[4][16];
    __shared__ float obuf[4][16][33];

    bf16x8 qfrag = *(const bf16x8*)(
        qb + ((size_t)(b * LL + i0 + l16)) * 256 + h * 32 + quad * 8);

    f32x4 O0 = {0.f,0.f,0.f,0.f}, O1 = {0.f,0.f,0.f,0.f};
    float mr[4] = {-1e30f,-1e30f,-1e30f,-1e30f};
    float lr[4] = {0.f,0.f,0.f,0.f};

    const float scale = 0.17677669529663687f; // 1/sqrt(32)
    const int jbase = wave * 192;
    const ushort_t* kp = kb + ((size_t)(b * LL + jbase)) * 256 + h * 32 + quad * 8;
    const ushort_t* vp = vt + (((size_t)(b * NH + h)) * 32 + l16) * LL + jbase + quad * 8;
    const ushort_t* pbp = pb
        + (((size_t)(b * 32 + n * NH + h)) * LL + (i0 + quad * 4)) * LL
        + jbase + l16;

    for (int jt = 0; jt < 6; ++jt) {
        int j0 = jt * 32;
        bf16x8 kf0 = *(const bf16x8*)(kp + (size_t)(j0 + l16) * 256);
        bf16x8 kf1 = *(const bf16x8*)(kp + (size_t)(j0 + 16 + l16) * 256);
        f32x4 s0 = __builtin_amdgcn_mfma_f32_16x16x32_bf16(qfrag, kf0, (f32x4){0.f,0.f,0.f,0.f}, 0, 0, 0);
        f32x4 s1 = __builtin_amdgcn_mfma_f32_16x16x32_bf16(qfrag, kf1, (f32x4){0.f,0.f,0.f,0.f}, 0, 0, 0);
        #pragma unroll
        for (int r = 0; r < 4; ++r) {
            float b0 = bf2f(pbp[(size_t)r * LL + j0]);
            float b1 = bf2f(pbp[(size_t)r * LL + j0 + 16]);
            s0[r] = s0[r] * scale + b0;
            s1[r] = s1[r] * scale + b1;
        }
        float tmax[4];
        #pragma unroll
        for (int r = 0; r < 4; ++r) tmax[r] = fmaxf(s0[r], s1[r]);
        #pragma unroll
        for (int mk = 1; mk <= 8; mk <<= 1) {
            #pragma unroll
            for (int r = 0; r < 4; ++r)
                tmax[r] = fmaxf(tmax[r], __shfl_xor(tmax[r], mk, 64));
        }
        #pragma unroll
        for (int r = 0; r < 4; ++r) {
            float mn = fmaxf(mr[r], tmax[r]);
            float c = __expf(mr[r] - mn);
            mr[r] = mn;
            lr[r] *= c;
            O0[r] *= c;
            O1[r] *= c;
        }
        float p0[4], p1[4], rs[4];
        #pragma unroll
        for (int r = 0; r < 4; ++r) {
            p0[r] = __expf(s0[r] - mr[r]);
            p1[r] = __expf(s1[r] - mr[r]);
            rs[r] = p0[r] + p1[r];
        }
        #pragma unroll
        for (int mk = 1; mk <= 8; mk <<= 1) {
            #pragma unroll
            for (int r = 0; r < 4; ++r)
                rs[r] += __shfl_xor(rs[r], mk, 64);
        }
        #pragma unroll
        for (int r = 0; r < 4; ++r) lr[r] += rs[r];
        #pragma unroll
        for (int r = 0; r < 4; ++r) {
            int qr = quad * 4 + r;
            ushort_t h0 = f2bf(p0[r]);
            ushort_t h1 = f2bf(p1[r]);
            Plds[wave][0][qr][l16]      = h0;
            Plds[wave][0][qr][16 + l16] = h1;
            Plds[wave][1][qr][l16]      = f2bf(p0[r] - bf2f(h0));
            Plds[wave][1][qr][16 + l16] = f2bf(p1[r] - bf2f(h1));
        }
        asm volatile("" ::: "memory");
        bf16x8 pfh = *(const bf16x8*)&Plds[wave][0][l16][quad * 8];
        bf16x8 pfl = *(const bf16x8*)&Plds[wave][1][l16][quad * 8];
        asm volatile("" ::: "memory");
        bf16x8 vf0 = *(const bf16x8*)(vp + j0);
        bf16x8 vf1 = *(const bf16x8*)(vp + (size_t)16 * LL + j0);
        O0 = __builtin_amdgcn_mfma_f32_16x16x32_bf16(pfh, vf0, O0, 0, 0, 0);
        O0 = __builtin_amdgcn_mfma_f32_16x16x32_bf16(pfl, vf0, O0, 0, 0, 0);
        O1 = __builtin_amdgcn_mfma_f32_16x16x32_bf16(pfh, vf1, O1, 0, 0, 0);
        O1 = __builtin_amdgcn_mfma_f32_16x16x32_bf16(pfl, vf1, O1, 0, 0, 0);
    }

    if (l16 == 0) {
        #pragma unroll
        for (int r = 0; r < 4; ++r) {
            mbuf[wave][quad * 4 + r] = mr[r];
            lbuf[wave][quad * 4 + r] = lr[r];
        }
    }
    #pragma unroll
    for (int r = 0; r < 4; ++r) {
        obuf[wave][quad * 4 + r][l16]      = O0[r];
        obuf[wave][quad * 4 + r][16 + l16] = O1[r];
    }
    __syncthreads();

    {
        int q = t >> 4;            // 0..15
        int d0 = (t & 15) * 2;
        float m0 = mbuf[0][q], m1 = mbuf[1][q], m2 = mbuf[2][q], m3 = mbuf[3][q];
        float M = fmaxf(fmaxf(m0, m1), fmaxf(m2, m3));
        float w0 = __expf(m0 - M), w1 = __expf(m1 - M);
        float w2 = __expf(m2 - M), w3 = __expf(m3 - M);
        float lt = lbuf[0][q] * w0 + lbuf[1][q] * w1 + lbuf[2][q] * w2 + lbuf[3][q] * w3;
        float inv = 1.0f / lt;
        float oa = obuf[0][q][d0] * w0 + obuf[1][q][d0] * w1
                 + obuf[2][q][d0] * w2 + obuf[3][q][d0] * w3;
        float ob = obuf[0][q][d0+1] * w0 + obuf[1][q][d0+1] * w1
                 + obuf[2][q][d0+1] * w2 + obuf[3][q][d0+1] * w3;
        ushort2 st;
        st.x = f2bf(oa * inv);
        st.y = f2bf(ob * inv);
        *reinterpret_cast<ushort2*>(
            outp + ((size_t)(b * LL + i0 + q)) * 256 + h * 32 + d0) = st;
    }
}

// ---------------- fallback fused attention (fp32 out) -----------------------
__global__ __launch_bounds__(256) void k_attn(
        const float* __restrict__ q, const float* __restrict__ kk,
        const float* __restrict__ v, const float* __restrict__ pair,
        const float* __restrict__ pw, float* __restrict__ outp) {
    int blk = blockIdx.x;
    int b = blk / LL, i = blk % LL;
    int tid = threadIdx.x;
    __shared__ float q_s[256];
    __shared__ float pw_s[CZ * NH];
    __shared__ float lg[NH][LL];
    __shared__ float part[8][256];
    __shared__ float invs[NH];
    size_t rowq = (size_t)(b * LL + i) * 256;
    q_s[tid] = q[rowq + tid];
    pw_s[tid] = pw[tid];
    pw_s[tid + 256] = pw[tid + 256];
    __syncthreads();

    const float scale = 0.17677669529663687f;
    for (int j = tid; j < LL; j += 256) {
        const float4* k4 = reinterpret_cast<const float4*>(kk + (size_t)(b * LL + j) * 256);
        const float4* q4 = reinterpret_cast<const float4*>(q_s);
        float dot[NH];
        #pragma unroll
        for (int h = 0; h < NH; ++h) {
            float sx = 0.f, sy = 0.f, sz = 0.f, sw = 0.f;
            #pragma unroll
            for (int dd = 0; dd < 8; ++dd) {
                float4 kv = k4[h * 8 + dd];
                float4 qv = q4[h * 8 + dd];
                sx += qv.x * kv.x; sy += qv.y * kv.y;
                sz += qv.z * kv.z; sw += qv.w * kv.w;
            }
            dot[h] = (sx + sy) + (sz + sw);
        }
        const float4* p4 = reinterpret_cast<const float4*>(
            pair + ((size_t)(b * LL + i) * LL + j) * CZ);
        float bias[NH];
        #pragma unroll
        for (int h = 0; h < NH; ++h) bias[h] = 0.f;
        #pragma unroll
        for (int c4 = 0; c4 < 16; ++c4) {
            float4 pv = p4[c4];
            int c = c4 * 4;
            #pragma unroll
            for (int h = 0; h < NH; ++h)
                bias[h] += pv.x * pw_s[(c + 0) * NH + h] + pv.y * pw_s[(c + 1) * NH + h]
                         + pv.z * pw_s[(c + 2) * NH + h] + pv.w * pw_s[(c + 3) * NH + h];
        }
        #pragma unroll
        for (int h = 0; h < NH; ++h) lg[h][j] = dot[h] * scale + bias[h];
    }
    __syncthreads();

    int wave = tid >> 6, lane = tid & 63;
    for (int h = wave; h < NH; h += 4) {
        float mx = -1e30f;
        for (int j = lane; j < LL; j += 64) mx = fmaxf(mx, lg[h][j]);
        #pragma unroll
        for (int off = 32; off > 0; off >>= 1) mx = fmaxf(mx, __shfl_xor(mx, off, 64));
        float sm = 0.f;
        for (int j = lane; j < LL; j += 64) {
            float e = __expf(lg[h][j] - mx);
            lg[h][j] = e;
            sm += e;
        }
        #pragma unroll
        for (int off = 32; off > 0; off >>= 1) sm += __shfl_xor(sm, off, 64);
        if (lane == 0) invs[h] = 1.0f / sm;
    }
    __syncthreads();

    int g = tid >> 5, d = tid & 31;
    float acc[NH];
    #pragma unroll
    for (int h = 0; h < NH; ++h) acc[h] = 0.f;
    for (int j = g; j < LL; j += 8) {
        const float* vr = v + (size_t)(b * LL + j) * 256;
        #pragma unroll
        for (int h = 0; h < NH; ++h) acc[h] += lg[h][j] * vr[h * 32 + d];
    }
    #pragma unroll
    for (int h = 0; h < NH; ++h) part[g][h * 32 + d] = acc[h];
    __syncthreads();
    float sum = 0.f;
    #pragma unroll
    for (int g2 = 0; g2 < 8; ++g2) sum += part[g2][tid];
    outp[rowq + tid] = sum * invs[tid >> 5];
}

// ---------------- final frame update (wave per row) -------------------------
__global__ __launch_bounds__(256) void k_final(
        const float* __restrict__ h, const float* __restrict__ out_w,
        const float* __restrict__ out_b, const float* __restrict__ rots,
        const float* __restrict__ trans, float* __restrict__ out) {
    __shared__ float w_s[256 * 6];
    int t = threadIdx.x, wave = t >> 6, lane = t & 63;
    for (int i = t; i < 1536; i += 256) w_s[i] = out_w[i];
    __syncthreads();
    int row = blockIdx.x * 4 + wave;
    const float* hr = h + (size_t)row * 256;
    float4 hv = reinterpret_cast<const float4*>(hr)[lane];
    int k0 = lane * 4;
    float c[6];
    #pragma unroll
    for (int cc = 0; cc < 6; ++cc)
        c[cc] = hv.x * w_s[(k0+0)*6+cc] + hv.y * w_s[(k0+1)*6+cc]
              + hv.z * w_s[(k0+2)*6+cc] + hv.w * w_s[(k0+3)*6+cc];
    #pragma unroll
    for (int off = 32; off > 0; off >>= 1)
        #pragma unroll
        for (int cc = 0; cc < 6; ++cc)
            c[cc] += __shfl_xor(c[cc], off, 64);
    if (lane == 0) {
        float corr[6];
        #pragma unroll
        for (int cc = 0; cc < 6; ++cc) corr[cc] = c[cc] + out_b[cc];
        float vx = corr[0], vy = corr[1], vz = corr[2];
        float n = sqrtf(vx * vx + vy * vy + vz * vz);
        float inv = 1.0f / (n + 1e-8f);
        float ax = vx * inv, ay = vy * inv, az = vz * inv;
        float s = sinf(n), ccs = 1.0f - cosf(n);
        float K[9] = {0.f, -az, ay,  az, 0.f, -ax,  -ay, ax, 0.f};
        float K2[9];
        #pragma unroll
        for (int ii = 0; ii < 3; ++ii)
            #pragma unroll
            for (int jj = 0; jj < 3; ++jj)
                K2[ii * 3 + jj] = K[ii * 3 + 0] * K[0 * 3 + jj]
                                + K[ii * 3 + 1] * K[1 * 3 + jj]
                                + K[ii * 3 + 2] * K[2 * 3 + jj];
        float R[9];
        #pragma unroll
        for (int ii = 0; ii < 3; ++ii)
            #pragma unroll
            for (int jj = 0; jj < 3; ++jj)
                R[ii * 3 + jj] = (ii == jj ? 1.0f : 0.0f) + s * K[ii * 3 + jj] + ccs * K2[ii * 3 + jj];
        const float* ro = rots + (size_t)row * 9;
        float* o = out + (size_t)row * 12;
        #pragma unroll
        for (int ii = 0; ii < 3; ++ii)
            #pragma unroll
            for (int jj = 0; jj < 3; ++jj)
                o[ii * 3 + jj] = ro[ii * 3 + 0] * R[0 * 3 + jj]
                               + ro[ii * 3 + 1] * R[1 * 3 + jj]
                               + ro[ii * 3 + 2] * R[2 * 3 + jj];
        float t0 = corr[3], t1 = corr[4], t2 = corr[5];
        const float* tr = trans + (size_t)row * 3;
        #pragma unroll
        for (int ii = 0; ii < 3; ++ii)
            o[9 + ii] = ro[ii * 3 + 0] * t0 + ro[ii * 3 + 1] * t1 + ro[ii * 3 + 2] * t2 + tr[ii];
    }
}

extern "C" void kernel_launch(void* const* d_in, const int* in_sizes, int n_in,
                              void* d_out, int out_size, void* d_ws, size_t ws_size,
                              hipStream_t stream) {
    (void)in_sizes; (void)n_in; (void)out_size;
    const float* rots     = (const float*)d_in[0];
    const float* trans    = (const float*)d_in[1];
    const float* t        = (const float*)d_in[2];
    const float* single   = (const float*)d_in[3];
    const float* pair     = (const float*)d_in[4];
    const float* frame_w  = (const float*)d_in[5];
    const float* frame_b  = (const float*)d_in[6];
    const float* single_w = (const float*)d_in[7];
    const float* single_b = (const float*)d_in[8];
    const float* tw1      = (const float*)d_in[9];
    const float* tb1      = (const float*)d_in[10];
    const float* tw2      = (const float*)d_in[11];
    const float* tb2      = (const float*)d_in[12];
    const float* out_w    = (const float*)d_in[13];
    const float* out_b    = (const float*)d_in[14];
    const float* ag1      = (const float*)d_in[15];
    const float* abeta1   = (const float*)d_in[16];
    const float* apw1     = (const float*)d_in[17];
    const float* apb1     = (const float*)d_in[18];
    const float* wq       = (const float*)d_in[19];
    const float* wk       = (const float*)d_in[20];
    const float* wv       = (const float*)d_in[21];
    const float* pw       = (const float*)d_in[22];
    const float* wo       = (const float*)d_in[23];
    const float* wob      = (const float*)d_in[24];
    const float* ag2      = (const float*)d_in[25];
    const float* abeta2   = (const float*)d_in[26];
    const float* apw2     = (const float*)d_in[27];
    const float* apb2     = (const float*)d_in[28];
    const float* fw1      = (const float*)d_in[29];
    const float* fb1      = (const float*)d_in[30];
    const float* fw2      = (const float*)d_in[31];
    const float* fb2      = (const float*)d_in[32];

    float* ws = (float*)d_ws;
    float* time_cond = ws;                    // 512
    float* ss1 = time_cond + 512;             // 4096
    float* ss2 = ss1 + 4096;                  // 4096
    float* h   = ss2 + 4096;                  // 393216
    float* hh  = h + 393216;                  // (fallback only)
    float* q   = hh + 393216;
    float* k_  = q + 393216;
    float* v   = k_ + 393216;
    float* attnout = v + 393216;              // (fallback only)
    float* mid = attnout + 393216;            // 1572864 (fallback FFN; big: time scratch)
    float* pbf = mid + 1572864;               // 37748736 floats region (pb lives here)

    float* tmid    = mid;                     // 2048 (time chain scratch)

    const size_t base_floats = 3940864ull;
    const size_t pb_floats = 37748736ull;
    ushort_t* us = (ushort_t*)(ws + base_floats + pb_floats);
    ushort_t* hh_bf      = us;                 // 393216
    ushort_t* attnout_bf = hh_bf + 393216;     // 393216
    ushort_t* mid_bf     = attnout_bf + 393216;// 1572864
    ushort_t* wqkv_bt    = mid_bf + 1572864;   // 786432
    ushort_t* wo_bt      = wqkv_bt + 786432;   // 262144
    ushort_t* fw1_bt     = wo_bt + 262144;     // 1048576
    ushort_t* fw2_bt     = fw1_bt + 1048576;   // 1048576
    const size_t us_count = 5505024ull;

    // bf16 buffers aliasing big-path-unused fp32 regions
    ushort_t* qb    = (ushort_t*)q;            // [1536][256] bf16
    ushort_t* kbb   = (ushort_t*)k_;           // [1536][256] bf16
    ushort_t* vtb   = (ushort_t*)v;            // [2][8][32][768] bf16 (V^T)
    ushort_t* pb_bf = (ushort_t*)pbf;          // [2][32][768][768] bf16 (75.5 MB)

    const size_t need = (base_floats + pb_floats) * 4ull + us_count * 2ull;
    const bool big = ws_size >= need;

    k_zero<<<1, 512, 0, stream>>>(tmid, time_cond, ss1, ss2);
    k_time1<<<dim3(8, BB), 256, 0, stream>>>(t, tw1, tmid);
    k_time2<<<dim3(16, BB), 256, 0, stream>>>(tmid, tb1, tw2, tb2, time_cond);
    k_ss<<<dim3(32, BB, 2), 512, 0, stream>>>(time_cond, apw1, apb1, apw2, apb2, ss1, ss2);
    k_init_h<<<BL, 256, 0, stream>>>(rots, trans, single, frame_w, frame_b,
                                     single_w, single_b, h);
    if (big) {
        k_wt<<<dim3(64, NBLK, 6), 256, 0, stream>>>(wq, wk, wv, wo, fw1, fw2,
                                                    wqkv_bt, wo_bt, fw1_bt, fw2_bt);
        k_pairbias<<<BL, 256, 0, stream>>>(pair, pw, pb_bf);
        for (int n = 0; n < NBLK; ++n) {
            k_adaln_bf<<<BL, 256, 0, stream>>>(h, ag1 + n * 256, abeta1 + n * 256,
                                               ss1 + (size_t)n * BB * 512, hh_bf);
            k_mfma<8, 0><<<dim3(24, 12), 256, 0, stream>>>(
                hh_bf, wqkv_bt + (size_t)n * 196608, nullptr,
                nullptr, qb, kbb, vtb);
            k_attn_mfma<<<dim3(48, NH, BB), 256, 0, stream>>>(
                qb, kbb, vtb, pb_bf, n, attnout_bf);
            k_mfma32<8><<<dim3(48, 8), 256, 0, stream>>>(
                attnout_bf, wo_bt + (size_t)n * 65536, wob + n * 256, h, h);
            k_adaln_bf<<<BL, 256, 0, stream>>>(h, ag2 + n * 256, abeta2 + n * 256,
                                               ss2 + (size_t)n * BB * 512, hh_bf);
            k_mfma<8, 2><<<dim3(24, 16), 256, 0, stream>>>(
                hh_bf, fw1_bt + (size_t)n * 262144, fb1 + n * 1024,
                mid_bf, nullptr, nullptr, nullptr);
            k_mfma32<32><<<dim3(48, 8), 256, 0, stream>>>(
                mid_bf, fw2_bt + (size_t)n * 262144, fb2 + n * 256, h, h);
        }
    } else {
        for (int n = 0; n < NBLK; ++n) {
            k_adaln<<<BL, 256, 0, stream>>>(h, ag1 + n * 256, abeta1 + n * 256,
                                            ss1 + (size_t)n * BB * 512, hh);
            k_gemm_qkv<<<BL / 4, 256, 0, stream>>>(hh, wq + (size_t)n * 65536,
                                                   wk + (size_t)n * 65536,
                                                   wv + (size_t)n * 65536, q, k_, v);
            k_attn<<<BL, 256, 0, stream>>>(q, k_, v, pair, pw + n * 512, attnout);
            k_gemm4<1, 1><<<BL / 4, 256, 0, stream>>>(attnout, wo + (size_t)n * 65536,
                                                      wob + n * 256, h, h, 1 | 4);
            k_adaln<<<BL, 256, 0, stream>>>(h, ag2 + n * 256, abeta2 + n * 256,
                                            ss2 + (size_t)n * BB * 512, hh);
            k_gemm4<4, 1><<<BL / 4, 256, 0, stream>>>(hh, fw1 + (size_t)n * 262144,
                                                      fb1 + n * 1024, nullptr, mid, 1 | 2);
            k_gemm4<1, 4><<<BL / 4, 256, 0, stream>>>(mid, fw2 + (size_t)n * 262144,
                                                      fb2 + n * 256, h, h, 1 | 4);
        }
    }
    k_final<<<BL / 4, 256, 0, stream>>>(h, out_w, out_b, rots, trans, (float*)d_out);
}